// Round 10
// baseline (194.512 us; speedup 1.0000x reference)
//
#include <hip/hip_runtime.h>
#include <math.h>

#define D 256
#define NX 16
#define L 2048
#define NBATCH 8
#define NTOK (NBATCH * L)
#define CL 32
#define NCH (L / CL)  // 64
#define LOG2E 1.44269504088896340736f

typedef float f32x4 __attribute__((ext_vector_type(4)));
// Fragment type for mfma_f32_16x16x32_bf16 on gfx950: 8 bf16 as 8 shorts.
typedef short bf16x8 __attribute__((ext_vector_type(8)));

// round-to-nearest-even f32 -> bf16 (as ushort bits)
__device__ __forceinline__ unsigned short f2bf(float x) {
  unsigned u = __float_as_uint(x);
  u = u + 0x7fffu + ((u >> 16) & 1u);
  return (unsigned short)(u >> 16);
}
__device__ __forceinline__ float bf2f(unsigned short h) {
  return __uint_as_float(((unsigned)h) << 16);
}

// ---------------- K0: At prep + weight fragment packing + LN2-fold vectors --
__global__ __launch_bounds__(256) void k0_prep(const float* __restrict__ A,
                                               const float* __restrict__ WB,
                                               const float* __restrict__ WC,
                                               const float* __restrict__ Win,
                                               const float* __restrict__ W1,
                                               const float* __restrict__ W2,
                                               const float* __restrict__ nfg,
                                               const float* __restrict__ nfb,
                                               float* __restrict__ At,
                                               unsigned short* __restrict__ W1fh,
                                               unsigned short* __restrict__ W1fl,
                                               unsigned short* __restrict__ W2fh,
                                               unsigned short* __restrict__ W2fl,
                                               unsigned short* __restrict__ Winfh,
                                               unsigned short* __restrict__ Winfl,
                                               unsigned short* __restrict__ Wbcfh,
                                               unsigned short* __restrict__ Wbcfl,
                                               float* __restrict__ u1,
                                               float* __restrict__ v1) {
  int i = blockIdx.x * 256 + threadIdx.x;  // 94720 total
  if (i < 4096) {
    int d = i >> 4, n = i & 15;
    At[n * D + d] = A[i] * LOG2E;
  } else if (i < 12288) {
    // Win frags (B of phase A, K=32): e = (tt*64 + l)*8 + j, tt=0..15
    int e = i - 4096;
    int j = e & 7, l = (e >> 3) & 63, tt = e >> 9;
    int k = ((l >> 4) << 3) + j;        // K=32, single K-step
    int n = tt * 16 + (l & 15);
    float x = Win[k * 256 + n];
    unsigned short h = f2bf(x);
    Winfh[e] = h;
    Winfl[e] = f2bf(x - bf2f(h));
  } else if (i < 20480) {
    // Wbct frags (B of phase C): e = ((s*2+tt)*64 + l)*8 + j
    int e = i - 12288;
    int j = e & 7, l = (e >> 3) & 63, q = e >> 9;  // q = s*2+tt
    int s = q >> 1, tt = q & 1;
    int k = s * 32 + ((l >> 4) << 3) + j;
    int n = tt * 16 + (l & 15);
    float x = (n < 16) ? WB[n * 256 + k] : WC[(n - 16) * 256 + k];
    unsigned short h = f2bf(x);
    Wbcfh[e] = h;
    Wbcfl[e] = f2bf(x - bf2f(h));
  } else if (i < 86016) {
    // W1 frags (nfg-folded): e = ((s*16 + t)*64 + l)*8 + j ; 65536 elems
    int e = i - 20480;
    int j = e & 7, l = (e >> 3) & 63, tt = (e >> 9) & 15, s = e >> 13;
    int k = s * 32 + ((l >> 4) << 3) + j;
    int n = tt * 16 + (l & 15);
    float x = W1[k * 256 + n] * nfg[k];
    unsigned short h = f2bf(x);
    W1fh[e] = h;
    W1fl[e] = f2bf(x - bf2f(h));
  } else if (i < 94208) {
    // W2 frags: e = ((s*2 + t)*64 + l)*8 + j ; 8192 elems
    int e = i - 86016;
    int j = e & 7, l = (e >> 3) & 63, tt = (e >> 9) & 1, s = e >> 10;
    int k = s * 32 + ((l >> 4) << 3) + j;
    int n = tt * 16 + (l & 15);
    float x = W2[k * 32 + n];
    unsigned short h = f2bf(x);
    W2fh[e] = h;
    W2fl[e] = f2bf(x - bf2f(h));
  } else if (i < 94464) {
    int c = i - 94208;
    float s = 0.f;
    for (int d = 0; d < 256; ++d) s += nfg[d] * W1[d * 256 + c];
    u1[c] = s;
  } else if (i < 94720) {
    int c = i - 94464;
    float s = 0.f;
    for (int d = 0; d < 256; ++d) s += nfb[d] * W1[d * 256 + c];
    v1[c] = s;
  }
}

// ---------------- K1A: MFMA front end + LOCAL SCAN + p_local, 512 thr ------
// New vs r9: scan (t<256, full 16-n) also accumulates p_local = x·C and
// writes vpart = h + p_local (pre-LN2 partial) to global instead of hn.
// cds (inclusive delta prefix) written per token. Bm global write dropped
// (k2cd no longer needs B); Cm kept (k2cd reads it scalar).
__global__ __launch_bounds__(512, 4) void k1a_front_scan(
    const float* __restrict__ y, const float* __restrict__ bin_,
    const float* __restrict__ ng, const float* __restrict__ nb,
    const float* __restrict__ qd, const float* __restrict__ pd,
    const float* __restrict__ At,
    const unsigned short* __restrict__ Winfh,
    const unsigned short* __restrict__ Winfl,
    const unsigned short* __restrict__ Wbcfh,
    const unsigned short* __restrict__ Wbcfl,
    float* __restrict__ vpart, float* __restrict__ cdsg,
    float* __restrict__ Cm,
    float* __restrict__ EX, float* __restrict__ T) {
  __shared__ float sy[32][36];       // y tile, padded pitch
  __shared__ float sh[32][260];      // hn tile f32, pitch 260
  __shared__ float sB[32][NX];
  __shared__ float sC[32][NX];
  __shared__ float sred[32][16];     // per-wave LN/delta partials
  __shared__ float sdelta[32];
  __shared__ float smu[32];
  __shared__ float srstd[32];
  __shared__ float ssig[32];
  __shared__ __align__(16) unsigned short sChA_h[32 * 256];  // hn bf16 hi (swz)
  __shared__ __align__(16) unsigned short sChA_l[32 * 256];  // hn bf16 lo (swz)
  int t = threadIdx.x;
  int l = t & 63;
  int w = t >> 6;
  int tok0 = blockIdx.x * 32;
  // 1. stage y (32x32 f32)
  if (t < 256) {
    *(float4*)&sy[t >> 3][(t & 7) * 4] =
        ((const float4*)(y + (size_t)tok0 * 32))[t];
  }
  __syncthreads();
  // 2. phase A MFMA: build y A-frags (hi/lo), Win B-frags from global
  f32x4 acc[2][2];
  {
    bf16x8 yah[2], yal[2];
    int k0 = (l >> 4) << 3;
    #pragma unroll
    for (int m = 0; m < 2; ++m) {
      int row = m * 16 + (l & 15);
      float4 f0 = *(float4*)&sy[row][k0];
      float4 f1 = *(float4*)&sy[row][k0 + 4];
      float v0 = f0.x, v1_ = f0.y, v2 = f0.z, v3 = f0.w;
      float v4 = f1.x, v5 = f1.y, v6 = f1.z, v7 = f1.w;
      unsigned short h0 = f2bf(v0), h1 = f2bf(v1_), h2 = f2bf(v2), h3 = f2bf(v3);
      unsigned short h4 = f2bf(v4), h5 = f2bf(v5), h6 = f2bf(v6), h7 = f2bf(v7);
      yah[m][0] = (short)h0; yah[m][1] = (short)h1; yah[m][2] = (short)h2; yah[m][3] = (short)h3;
      yah[m][4] = (short)h4; yah[m][5] = (short)h5; yah[m][6] = (short)h6; yah[m][7] = (short)h7;
      yal[m][0] = (short)f2bf(v0 - bf2f(h0)); yal[m][1] = (short)f2bf(v1_ - bf2f(h1));
      yal[m][2] = (short)f2bf(v2 - bf2f(h2)); yal[m][3] = (short)f2bf(v3 - bf2f(h3));
      yal[m][4] = (short)f2bf(v4 - bf2f(h4)); yal[m][5] = (short)f2bf(v5 - bf2f(h5));
      yal[m][6] = (short)f2bf(v6 - bf2f(h6)); yal[m][7] = (short)f2bf(v7 - bf2f(h7));
    }
    const bf16x8* Bh = (const bf16x8*)Winfh;
    const bf16x8* Bl = (const bf16x8*)Winfl;
    #pragma unroll
    for (int n = 0; n < 2; ++n) {
      int tt = w * 2 + n;
      bf16x8 bh = Bh[tt * 64 + l];
      bf16x8 bl = Bl[tt * 64 + l];
      #pragma unroll
      for (int m = 0; m < 2; ++m) {
        f32x4 a = {0.f, 0.f, 0.f, 0.f};
        a = __builtin_amdgcn_mfma_f32_16x16x32_bf16(yah[m], bh, a, 0, 0, 0);
        a = __builtin_amdgcn_mfma_f32_16x16x32_bf16(yal[m], bh, a, 0, 0, 0);
        a = __builtin_amdgcn_mfma_f32_16x16x32_bf16(yah[m], bl, a, 0, 0, 0);
        a = __builtin_amdgcn_mfma_f32_16x16x32_bf16(yal[m], bl, a, 0, 0, 0);
        acc[m][n] = a;
      }
    }
  }
  // bias add: lane's two cols
  int c0 = w * 32 + (l & 15), c1 = c0 + 16;
  {
    float b0 = bin_[c0], b1v = bin_[c1];
    #pragma unroll
    for (int m = 0; m < 2; ++m)
      #pragma unroll
      for (int r = 0; r < 4; ++r) { acc[m][0][r] += b0; acc[m][1][r] += b1v; }
  }
  // 3. LN partial reduce over this wave's 32 cols (16-lane groups)
  {
    #pragma unroll
    for (int m = 0; m < 2; ++m)
      #pragma unroll
      for (int r = 0; r < 4; ++r) {
        float a0 = acc[m][0][r], a1 = acc[m][1][r];
        float s1 = a0 + a1;
        float s2 = a0 * a0 + a1 * a1;
        #pragma unroll
        for (int off = 1; off < 16; off <<= 1) {
          s1 += __shfl_xor(s1, off);
          s2 += __shfl_xor(s2, off);
        }
        if ((l & 15) == 0) {
          int tok = m * 16 + ((l >> 4) << 2) + r;
          sred[tok][w * 2] = s1;
          sred[tok][w * 2 + 1] = s2;
        }
      }
  }
  __syncthreads();
  // 4. combine partials -> mu, rstd, sigma (threads 0..31)
  if (t < 32) {
    float s1 = 0.f, s2 = 0.f;
    #pragma unroll
    for (int q = 0; q < 8; ++q) { s1 += sred[t][q * 2]; s2 += sred[t][q * 2 + 1]; }
    float mu = s1 * (1.f / D);
    float var = s2 * (1.f / D) - mu * mu;
    float rstd = rsqrtf(var + 1e-5f);
    smu[t] = mu;
    srstd[t] = rstd;
    ssig[t] = sqrtf(var + 1e-5f);
  }
  __syncthreads();
  // 5. hn = LN(h); write sh f32; delta partial reduce
  {
    float g0 = ng[c0], g1 = ng[c1];
    float nb0 = nb[c0], nb1 = nb[c1];
    float q0 = qd[c0], q1 = qd[c1];
    float ddv[2][4];
    #pragma unroll
    for (int m = 0; m < 2; ++m)
      #pragma unroll
      for (int r = 0; r < 4; ++r) {
        int tok = m * 16 + ((l >> 4) << 2) + r;
        float mu = smu[tok], rstd = srstd[tok];
        float h0 = (acc[m][0][r] - mu) * rstd * g0 + nb0;
        float h1 = (acc[m][1][r] - mu) * rstd * g1 + nb1;
        sh[tok][c0] = h0;
        sh[tok][c1] = h1;
        float dx = h0 * q0 + h1 * q1;
        #pragma unroll
        for (int off = 1; off < 16; off <<= 1) dx += __shfl_xor(dx, off);
        ddv[m][r] = dx;
      }
    if ((l & 15) == 0) {
      #pragma unroll
      for (int m = 0; m < 2; ++m)
        #pragma unroll
        for (int r = 0; r < 4; ++r)
          sred[m * 16 + ((l >> 4) << 2) + r][w] = ddv[m][r];
    }
  }
  __syncthreads();
  // 6. delta combine + INCLUSIVE PREFIX (cds) + T ; sh -> bf16 hi/lo swizzled
  if (t < 32) {
    float dsum = 0.f;
    #pragma unroll
    for (int q = 0; q < 8; ++q) dsum += sred[t][q];
    float xx = pd[0] + dsum;
    float dv = (xx > 20.f) ? xx : log1pf(expf(xx));
    sdelta[t] = dv;
    float c = dv;
    #pragma unroll
    for (int off = 1; off < 32; off <<= 1) {
      float o = __shfl_up(c, off);
      if (t >= off) c += o;
    }
    cdsg[tok0 + t] = c;
    if (t == 31) T[blockIdx.x] = c;
  }
  {
    int row = t & 31;
    int cq = (t >> 5) * 16;   // 16 cols per thread
    float4 f0 = *(float4*)&sh[row][cq];
    float4 f1 = *(float4*)&sh[row][cq + 4];
    float4 f2 = *(float4*)&sh[row][cq + 8];
    float4 f3 = *(float4*)&sh[row][cq + 12];
    float vv[16] = {f0.x, f0.y, f0.z, f0.w, f1.x, f1.y, f1.z, f1.w,
                    f2.x, f2.y, f2.z, f2.w, f3.x, f3.y, f3.z, f3.w};
    unsigned hw[8], lw[8];
    #pragma unroll
    for (int p = 0; p < 8; ++p) {
      unsigned short ha = f2bf(vv[2 * p]), hb = f2bf(vv[2 * p + 1]);
      unsigned short la = f2bf(vv[2 * p] - bf2f(ha));
      unsigned short lb = f2bf(vv[2 * p + 1] - bf2f(hb));
      hw[p] = (unsigned)ha | ((unsigned)hb << 16);
      lw[p] = (unsigned)la | ((unsigned)lb << 16);
    }
    unsigned base = (unsigned)row * 512;
    #pragma unroll
    for (int g = 0; g < 2; ++g) {
      unsigned off = ((unsigned)(cq * 2 + g * 16)) ^ ((unsigned)(row & 7) << 4);
      uint4 hv4 = {hw[g * 4], hw[g * 4 + 1], hw[g * 4 + 2], hw[g * 4 + 3]};
      uint4 lv4 = {lw[g * 4], lw[g * 4 + 1], lw[g * 4 + 2], lw[g * 4 + 3]};
      *(uint4*)((char*)sChA_h + base + off) = hv4;
      *(uint4*)((char*)sChA_l + base + off) = lv4;
    }
  }
  __syncthreads();
  // 7. phase C MFMA (waves 0-3): [Bm|Cm]; B,C -> LDS; Cm also -> global
  if (w < 4) {
    int mw = w & 1, nw = w >> 1;
    int row = mw * 16 + (l & 15);
    unsigned abase = (unsigned)row * 512;
    const bf16x8* B2h = (const bf16x8*)Wbcfh;
    const bf16x8* B2l = (const bf16x8*)Wbcfl;
    f32x4 acc2 = {0.f, 0.f, 0.f, 0.f};
    #pragma unroll
    for (int s = 0; s < 8; ++s) {
      unsigned off = ((unsigned)(s * 64 + ((l >> 4) << 4))) ^ ((unsigned)(row & 7) << 4);
      bf16x8 ah = *(const bf16x8*)((const char*)sChA_h + abase + off);
      bf16x8 al = *(const bf16x8*)((const char*)sChA_l + abase + off);
      int bi = (s * 2 + nw) * 64 + l;
      bf16x8 bh = B2h[bi];
      bf16x8 bl = B2l[bi];
      acc2 = __builtin_amdgcn_mfma_f32_16x16x32_bf16(ah, bh, acc2, 0, 0, 0);
      acc2 = __builtin_amdgcn_mfma_f32_16x16x32_bf16(al, bh, acc2, 0, 0, 0);
      acc2 = __builtin_amdgcn_mfma_f32_16x16x32_bf16(ah, bl, acc2, 0, 0, 0);
      acc2 = __builtin_amdgcn_mfma_f32_16x16x32_bf16(al, bl, acc2, 0, 0, 0);
    }
    int tokr = mw * 16 + ((l >> 4) << 2);
    int colc = l & 15;
    if (nw == 0) {
      #pragma unroll
      for (int r = 0; r < 4; ++r) sB[tokr + r][colc] = acc2[r];
    } else {
      #pragma unroll
      for (int r = 0; r < 4; ++r) {
        Cm[(size_t)(tok0 + tokr + r) * NX + colc] = acc2[r];
        sC[tokr + r][colc] = acc2[r];
      }
    }
  }
  __syncthreads();
  // 8. scan (t<256, full 16-n): x-state + p_local; vpart = h + p_local.
  if (t < 256) {
    int d = t;
    float a16v[16], x16v[16];
    size_t exbase = (size_t)blockIdx.x * (NX * D) + d;
    #pragma unroll
    for (int n = 0; n < 16; ++n) {
      a16v[n] = At[n * D + d];
      x16v[n] = 0.f;
    }
    float nb_d = nb[d];
    float invg = 1.0f / ng[d];
    float* vout = vpart + (size_t)tok0 * D + d;
    for (int lo = 0; lo < CL; ++lo) {
      float hnv = sh[lo][d];
      float dlt = sdelta[lo];
      float du = dlt * hnv;
      float Bv[16], Cvv[16];
      *(float4*)&Bv[0]  = *(float4*)&sB[lo][0];
      *(float4*)&Bv[4]  = *(float4*)&sB[lo][4];
      *(float4*)&Bv[8]  = *(float4*)&sB[lo][8];
      *(float4*)&Bv[12] = *(float4*)&sB[lo][12];
      *(float4*)&Cvv[0]  = *(float4*)&sC[lo][0];
      *(float4*)&Cvv[4]  = *(float4*)&sC[lo][4];
      *(float4*)&Cvv[8]  = *(float4*)&sC[lo][8];
      *(float4*)&Cvv[12] = *(float4*)&sC[lo][12];
      float p = 0.f;
      #pragma unroll
      for (int n = 0; n < 16; ++n) {
        x16v[n] = fmaf(exp2f(dlt * a16v[n]), x16v[n], du * Bv[n]);
        p = fmaf(x16v[n], Cvv[n], p);
      }
      float h = fmaf((hnv - nb_d) * invg, ssig[lo], smu[lo]);
      vout[(size_t)lo * D] = h + p;
    }
    #pragma unroll
    for (int n = 0; n < 16; ++n) EX[exbase + n * D] = x16v[n];
  }
}

// ---------------- K2b: chunk-level scan, 8-deep prefetch ring --------------
__global__ __launch_bounds__(64) void k2b_chunkscan(
    const float* __restrict__ At, const float* __restrict__ T,
    float* __restrict__ EX) {
  __shared__ float sT[NCH];
  int b = blockIdx.x >> 6;
  int rem = ((blockIdx.x & 63) << 6) | threadIdx.x;  // n*D + d
  sT[threadIdx.x] = T[b * NCH + threadIdx.x];
  __syncthreads();
  float A2 = At[rem];  // already *LOG2E
  size_t base = ((size_t)b << 18) + rem;
  float eq[8];
  #pragma unroll
  for (int j = 0; j < 8; ++j) eq[j] = EX[base + ((size_t)j << 12)];
  float x = 0.f;
  #pragma unroll 8
  for (int c = 0; c < NCH; ++c) {
    float e = eq[c & 7];
    if (c + 8 < NCH) eq[c & 7] = EX[base + ((size_t)(c + 8) << 12)];
    EX[base + ((size_t)c << 12)] = x;
    x = fmaf(exp2f(sT[c] * A2), x, e);
  }
}

__device__ __forceinline__ float gelu_exact(float x) {
  return 0.5f * x * (1.f + erff(x * 0.70710678118654752440f));
}

// ---------------- K2cd: PARALLEL FIXUP + LN2-FOLDED MFMA MLP, 512 thr -------
// No serial scan: v[tok][d] = vpart + sum_n Cm[tok][n]*exp2(cds[tok]*At)*xe[n]
// — fully parallel (thread (g=t>>8, d=t&255) handles 16 tokens). Cm/cds read
// via wave-uniform scalar loads (s_load; safe — written by a prior kernel).
// Then stats readback, GEMM1 (nfg-folded W1), affine epilogue, GEMM2.
__global__ __launch_bounds__(512, 4) void k2cd_scan_mlp(
    const float* __restrict__ vpart, const float* __restrict__ cdsg,
    const float* __restrict__ Cm,
    const float* __restrict__ At, const float* __restrict__ EX,
    const unsigned short* __restrict__ W1fh, const unsigned short* __restrict__ W1fl,
    const unsigned short* __restrict__ W2fh, const unsigned short* __restrict__ W2fl,
    const float* __restrict__ u1, const float* __restrict__ v1,
    const float* __restrict__ b1, const float* __restrict__ b2,
    float* __restrict__ out) {
  __shared__ __align__(16) unsigned short sAh[32 * 256]; // bf16 hi (x-tile, then z)
  __shared__ __align__(16) unsigned short sAl[32 * 256]; // bf16 lo
  __shared__ float srstd2[32];
  __shared__ float smur2[32];      // mu*rstd per token
  int t = threadIdx.x;
  int l = t & 63, w = t >> 6;
  int tok0 = blockIdx.x * 32;  // blockIdx.x == global chunk index
  size_t tokbase = (size_t)tok0;
  // ---- parallel fixup: thread (g, d) handles tokens g*16 .. g*16+15 ----
  {
    int g = t >> 8, d = t & 255;
    float a16v[16], xe[16];
    size_t exbase = (size_t)blockIdx.x * (NX * D) + d;
    #pragma unroll
    for (int n = 0; n < 16; ++n) {
      a16v[n] = At[n * D + d];
      xe[n] = EX[exbase + n * D];
    }
    const float* vp_base = vpart + (tokbase + g * 16) * D + d;
    #pragma unroll 4
    for (int q = 0; q < 16; ++q) {
      int tok = g * 16 + q;
      float vp = vp_base[(size_t)q * D];
      float ct = cdsg[tokbase + tok];           // uniform -> s_load
      float pf = 0.f;
      #pragma unroll
      for (int n = 0; n < 16; ++n) {
        float cv = Cm[(tokbase + tok) * NX + n];  // uniform -> s_load
        pf = fmaf(cv * exp2f(ct * a16v[n]), xe[n], pf);
      }
      float v = vp + pf;  // final pre-LN2 value, token tok, column d
      unsigned short vh = f2bf(v);
      unsigned short vl = f2bf(v - bf2f(vh));
      unsigned off16 = ((unsigned)(d * 2)) ^ ((unsigned)((tok & 7) << 4));
      *(unsigned short*)((char*)sAh + tok * 512 + off16) = vh;
      *(unsigned short*)((char*)sAl + tok * 512 + off16) = vl;
    }
  }
  __syncthreads();
  // stats phase: wave w handles tokens w*4..w*4+3; 64 lanes x 4 cols each
  {
    #pragma unroll
    for (int p = 0; p < 4; ++p) {
      int tok = w * 4 + p;
      unsigned off = ((unsigned)(l * 8)) ^ ((unsigned)((tok & 7) << 4));
      uint2 hv2 = *(uint2*)((char*)sAh + tok * 512 + off);
      uint2 lv2 = *(uint2*)((char*)sAl + tok * 512 + off);
      float v0 = bf2f((unsigned short)(hv2.x & 0xffff)) + bf2f((unsigned short)(lv2.x & 0xffff));
      float v1_ = bf2f((unsigned short)(hv2.x >> 16)) + bf2f((unsigned short)(lv2.x >> 16));
      float v2 = bf2f((unsigned short)(hv2.y & 0xffff)) + bf2f((unsigned short)(lv2.y & 0xffff));
      float v3 = bf2f((unsigned short)(hv2.y >> 16)) + bf2f((unsigned short)(lv2.y >> 16));
      float s1 = v0 + v1_ + v2 + v3;
      float s2 = v0 * v0 + v1_ * v1_ + v2 * v2 + v3 * v3;
      #pragma unroll
      for (int off2 = 1; off2 < 64; off2 <<= 1) {
        s1 += __shfl_xor(s1, off2);
        s2 += __shfl_xor(s2, off2);
      }
      if (l == 0) {
        float mu = s1 * (1.f / D);
        float var = s2 * (1.f / D) - mu * mu;
        float rstd = rsqrtf(var + 1e-5f);
        srstd2[tok] = rstd;
        smur2[tok] = mu * rstd;
      }
    }
  }
  __syncthreads();
  // ---- GEMM1: x (32x256) @ W1g (256x256); wave w owns cols [w*32,+32) ----
  const bf16x8* B1h = (const bf16x8*)W1fh;
  const bf16x8* B1l = (const bf16x8*)W1fl;
  f32x4 acc[2][2];
  #pragma unroll
  for (int m = 0; m < 2; ++m)
    #pragma unroll
    for (int n = 0; n < 2; ++n) {
      f32x4 z4 = {0.f, 0.f, 0.f, 0.f};
      acc[m][n] = z4;
    }
  #pragma unroll 2
  for (int s = 0; s < 8; ++s) {
    bf16x8 ah[2], al[2];
    #pragma unroll
    for (int m = 0; m < 2; ++m) {
      int row = m * 16 + (l & 15);
      unsigned off16 = ((unsigned)(s * 64 + ((l >> 4) << 4))) ^ ((unsigned)(row & 7) << 4);
      ah[m] = *(const bf16x8*)((const char*)sAh + row * 512 + off16);
      al[m] = *(const bf16x8*)((const char*)sAl + row * 512 + off16);
    }
    #pragma unroll
    for (int n = 0; n < 2; ++n) {
      int bi = (s * 16 + w * 2 + n) * 64 + l;
      bf16x8 bh = B1h[bi];
      bf16x8 bl = B1l[bi];
      #pragma unroll
      for (int m = 0; m < 2; ++m) {
        acc[m][n] = __builtin_amdgcn_mfma_f32_16x16x32_bf16(ah[m], bh, acc[m][n], 0, 0, 0);
        acc[m][n] = __builtin_amdgcn_mfma_f32_16x16x32_bf16(al[m], bh, acc[m][n], 0, 0, 0);
        acc[m][n] = __builtin_amdgcn_mfma_f32_16x16x32_bf16(ah[m], bl, acc[m][n], 0, 0, 0);
        acc[m][n] = __builtin_amdgcn_mfma_f32_16x16x32_bf16(al[m], bl, acc[m][n], 0, 0, 0);
      }
    }
  }
  __syncthreads();  // all A-tile reads done; sAh/sAl now reused for z
  // ---- LN2 affine + b1 + gelu -> z (bf16 hi/lo) back into sAh/sAl ----
  #pragma unroll
  for (int n = 0; n < 2; ++n) {
    int colz = w * 32 + n * 16 + (l & 15);
    float u1c = u1[colz];
    float v1c = v1[colz] + b1[colz];
    #pragma unroll
    for (int m = 0; m < 2; ++m) {
      #pragma unroll
      for (int r = 0; r < 4; ++r) {
        int row = m * 16 + ((l >> 4) << 2) + r;  // C/D: row=(lane>>4)*4+reg
        float zpre = acc[m][n][r] * srstd2[row] - smur2[row] * u1c + v1c;
        float zv = gelu_exact(zpre);
        unsigned short zh = f2bf(zv);
        unsigned short zl = f2bf(zv - bf2f(zh));
        unsigned off16 = ((unsigned)(colz * 2)) ^ ((unsigned)(row & 7) << 4);
        *(unsigned short*)((char*)sAh + row * 512 + off16) = zh;
        *(unsigned short*)((char*)sAl + row * 512 + off16) = zl;
      }
    }
  }
  __syncthreads();
  // ---- GEMM2: z (32x256) @ W2 (256x32); waves 0-3 -> (mw=w>>1, nw=w&1) ----
  if (w < 4) {
    int mw = w >> 1, nw = w & 1;
    const bf16x8* B2h = (const bf16x8*)W2fh;
    const bf16x8* B2l = (const bf16x8*)W2fl;
    f32x4 acc2 = {0.f, 0.f, 0.f, 0.f};
    #pragma unroll 2
    for (int s = 0; s < 8; ++s) {
      int row = mw * 16 + (l & 15);
      unsigned off16 = ((unsigned)(s * 64 + ((l >> 4) << 4))) ^ ((unsigned)(row & 7) << 4);
      bf16x8 zh8 = *(const bf16x8*)((const char*)sAh + row * 512 + off16);
      bf16x8 zl8 = *(const bf16x8*)((const char*)sAl + row * 512 + off16);
      int bi = (s * 2 + nw) * 64 + l;
      bf16x8 bh = B2h[bi];
      bf16x8 bl = B2l[bi];
      acc2 = __builtin_amdgcn_mfma_f32_16x16x32_bf16(zh8, bh, acc2, 0, 0, 0);
      acc2 = __builtin_amdgcn_mfma_f32_16x16x32_bf16(zl8, bh, acc2, 0, 0, 0);
      acc2 = __builtin_amdgcn_mfma_f32_16x16x32_bf16(zh8, bl, acc2, 0, 0, 0);
      acc2 = __builtin_amdgcn_mfma_f32_16x16x32_bf16(zl8, bl, acc2, 0, 0, 0);
    }
    int colo = nw * 16 + (l & 15);
    float b2v = b2[colo];
    #pragma unroll
    for (int r = 0; r < 4; ++r) {
      int row = mw * 16 + ((l >> 4) << 2) + r;
      out[(size_t)(tok0 + row) * 32 + colo] = acc2[r] + b2v;
    }
  }
}

extern "C" void kernel_launch(void* const* d_in, const int* in_sizes, int n_in,
                              void* d_out, int out_size, void* d_ws, size_t ws_size,
                              hipStream_t stream) {
  const float* y    = (const float*)d_in[0];
  const float* Win  = (const float*)d_in[1];
  const float* bin_ = (const float*)d_in[2];
  const float* ng   = (const float*)d_in[3];
  const float* nb   = (const float*)d_in[4];
  const float* A    = (const float*)d_in[5];
  const float* WB   = (const float*)d_in[6];
  const float* WC   = (const float*)d_in[7];
  const float* qd   = (const float*)d_in[8];
  const float* pd   = (const float*)d_in[9];
  const float* nfg  = (const float*)d_in[10];
  const float* nfb  = (const float*)d_in[11];
  const float* W1   = (const float*)d_in[12];
  const float* b1   = (const float*)d_in[13];
  const float* W2   = (const float*)d_in[14];
  const float* b2   = (const float*)d_in[15];

  float* ws = (float*)d_ws;
  float* vpart = ws;                          // NTOK*D (h + p_local)
  float* cdsg  = ws + 4194304;                // NTOK (inclusive delta prefix)
  float* Bm    = cdsg + NTOK;                 // NTOK*NX (unused slot, kept)
  float* Cm    = Bm + NTOK * NX;              // NTOK*NX
  float* muv   = Cm + NTOK * NX;              // NTOK (unused slot)
  float* irsv  = muv + NTOK;                  // NTOK (unused slot)
  float* Tbuf  = irsv + NTOK;                 // 512
  float* At    = Tbuf + NBATCH * NCH;         // 4096
  float* EX    = At + D * NX;                 // 512*4096 = 2M floats
  // bf16 fragment-packed weights (hi/lo)
  unsigned short* W1fh  = (unsigned short*)(EX + 2097152);  // 65536
  unsigned short* W1fl  = W1fh + 65536;                     // 65536
  unsigned short* W2fh  = W1fl + 65536;                     // 8192
  unsigned short* W2fl  = W2fh + 8192;                      // 8192
  unsigned short* Winfh = W2fl + 8192;                      // 8192
  unsigned short* Winfl = Winfh + 8192;                     // 8192
  unsigned short* Wbcfh = Winfl + 8192;                     // 8192
  unsigned short* Wbcfl = Wbcfh + 8192;                     // 8192
  float* u1 = (float*)(Wbcfl + 8192);                       // 256
  float* v1 = u1 + 256;                                     // 256

  k0_prep<<<370, 256, 0, stream>>>(A, WB, WC, Win, W1, W2, nfg, nfb, At,
                                   W1fh, W1fl, W2fh, W2fl,
                                   Winfh, Winfl, Wbcfh, Wbcfl, u1, v1);
  k1a_front_scan<<<NTOK / 32, 512, 0, stream>>>(y, bin_, ng, nb, qd, pd, At,
                                                Winfh, Winfl, Wbcfh, Wbcfl,
                                                vpart, cdsg, Cm, EX, Tbuf);
  k2b_chunkscan<<<NBATCH * 64, 64, 0, stream>>>(At, Tbuf, EX);
  k2cd_scan_mlp<<<NTOK / 32, 512, 0, stream>>>(vpart, cdsg, Cm, At, EX,
                                               W1fh, W1fl, W2fh, W2fl,
                                               u1, v1, b1, b2, (float*)d_out);
}

// Round 11
// 192.020 us; speedup vs baseline: 1.0130x; 1.0130x over previous
//
#include <hip/hip_runtime.h>
#include <math.h>

#define D 256
#define NX 16
#define L 2048
#define NBATCH 8
#define NTOK (NBATCH * L)
#define CL 32
#define NCH (L / CL)  // 64
#define LOG2E 1.44269504088896340736f

typedef float f32x4 __attribute__((ext_vector_type(4)));
// Fragment type for mfma_f32_16x16x32_bf16 on gfx950: 8 bf16 as 8 shorts.
typedef short bf16x8 __attribute__((ext_vector_type(8)));

// round-to-nearest-even f32 -> bf16 (as ushort bits)
__device__ __forceinline__ unsigned short f2bf(float x) {
  unsigned u = __float_as_uint(x);
  u = u + 0x7fffu + ((u >> 16) & 1u);
  return (unsigned short)(u >> 16);
}
__device__ __forceinline__ float bf2f(unsigned short h) {
  return __uint_as_float(((unsigned)h) << 16);
}

// ---------------- K0: At prep + weight fragment packing + LN2-fold vectors --
__global__ __launch_bounds__(256) void k0_prep(const float* __restrict__ A,
                                               const float* __restrict__ WB,
                                               const float* __restrict__ WC,
                                               const float* __restrict__ Win,
                                               const float* __restrict__ W1,
                                               const float* __restrict__ W2,
                                               const float* __restrict__ nfg,
                                               const float* __restrict__ nfb,
                                               float* __restrict__ At,
                                               unsigned short* __restrict__ W1fh,
                                               unsigned short* __restrict__ W1fl,
                                               unsigned short* __restrict__ W2fh,
                                               unsigned short* __restrict__ W2fl,
                                               unsigned short* __restrict__ Winfh,
                                               unsigned short* __restrict__ Winfl,
                                               unsigned short* __restrict__ Wbcfh,
                                               unsigned short* __restrict__ Wbcfl,
                                               float* __restrict__ u1,
                                               float* __restrict__ v1) {
  int i = blockIdx.x * 256 + threadIdx.x;  // 94720 total
  if (i < 4096) {
    int d = i >> 4, n = i & 15;
    At[n * D + d] = A[i] * LOG2E;
  } else if (i < 12288) {
    // Win frags (B of phase A, K=32): e = (tt*64 + l)*8 + j, tt=0..15
    int e = i - 4096;
    int j = e & 7, l = (e >> 3) & 63, tt = e >> 9;
    int k = ((l >> 4) << 3) + j;        // K=32, single K-step
    int n = tt * 16 + (l & 15);
    float x = Win[k * 256 + n];
    unsigned short h = f2bf(x);
    Winfh[e] = h;
    Winfl[e] = f2bf(x - bf2f(h));
  } else if (i < 20480) {
    // Wbct frags (B of phase C): e = ((s*2+tt)*64 + l)*8 + j
    int e = i - 12288;
    int j = e & 7, l = (e >> 3) & 63, q = e >> 9;  // q = s*2+tt
    int s = q >> 1, tt = q & 1;
    int k = s * 32 + ((l >> 4) << 3) + j;
    int n = tt * 16 + (l & 15);
    float x = (n < 16) ? WB[n * 256 + k] : WC[(n - 16) * 256 + k];
    unsigned short h = f2bf(x);
    Wbcfh[e] = h;
    Wbcfl[e] = f2bf(x - bf2f(h));
  } else if (i < 86016) {
    // W1 frags (nfg-folded): e = ((s*16 + t)*64 + l)*8 + j ; 65536 elems
    int e = i - 20480;
    int j = e & 7, l = (e >> 3) & 63, tt = (e >> 9) & 15, s = e >> 13;
    int k = s * 32 + ((l >> 4) << 3) + j;
    int n = tt * 16 + (l & 15);
    float x = W1[k * 256 + n] * nfg[k];
    unsigned short h = f2bf(x);
    W1fh[e] = h;
    W1fl[e] = f2bf(x - bf2f(h));
  } else if (i < 94208) {
    // W2 frags: e = ((s*2 + t)*64 + l)*8 + j ; 8192 elems
    int e = i - 86016;
    int j = e & 7, l = (e >> 3) & 63, tt = (e >> 9) & 1, s = e >> 10;
    int k = s * 32 + ((l >> 4) << 3) + j;
    int n = tt * 16 + (l & 15);
    float x = W2[k * 32 + n];
    unsigned short h = f2bf(x);
    W2fh[e] = h;
    W2fl[e] = f2bf(x - bf2f(h));
  } else if (i < 94464) {
    int c = i - 94208;
    float s = 0.f;
    for (int d = 0; d < 256; ++d) s += nfg[d] * W1[d * 256 + c];
    u1[c] = s;
  } else if (i < 94720) {
    int c = i - 94464;
    float s = 0.f;
    for (int d = 0; d < 256; ++d) s += nfb[d] * W1[d * 256 + c];
    v1[c] = s;
  }
}

// ---------------- K1A: MFMA front end + LOCAL SCAN, 512 thr, 3 blk/CU ------
// r10 + (a) NO f32 hn tile: step 5 writes hn straight to swizzled bf16 hi/lo
// sChA (step-6 conversion pass deleted; scan reconstructs hn = hi+lo, err
// ~2^-17); (b) scan on ALL 8 waves, 8-n halves, two vpart planes. LDS
// ~44 KB -> 3 blocks/CU (launch_bounds(512,6), ~70 VGPR).
__global__ __launch_bounds__(512, 6) void k1a_front_scan(
    const float* __restrict__ y, const float* __restrict__ bin_,
    const float* __restrict__ ng, const float* __restrict__ nb,
    const float* __restrict__ qd, const float* __restrict__ pd,
    const float* __restrict__ At,
    const unsigned short* __restrict__ Winfh,
    const unsigned short* __restrict__ Winfl,
    const unsigned short* __restrict__ Wbcfh,
    const unsigned short* __restrict__ Wbcfl,
    float* __restrict__ vpart0, float* __restrict__ vpart1,
    float* __restrict__ cdsg, float* __restrict__ Cm,
    float* __restrict__ EX, float* __restrict__ T) {
  __shared__ float sy[32][36];       // y tile, padded pitch
  __shared__ float sB[32][NX];
  __shared__ float sC[32][NX];
  __shared__ float sred[32][16];     // per-wave LN/delta partials
  __shared__ float sdelta[32];
  __shared__ float smu[32];
  __shared__ float srstd[32];
  __shared__ float ssig[32];
  __shared__ __align__(16) unsigned short sChA_h[32 * 256];  // hn bf16 hi (swz)
  __shared__ __align__(16) unsigned short sChA_l[32 * 256];  // hn bf16 lo (swz)
  int t = threadIdx.x;
  int l = t & 63;
  int w = t >> 6;
  int tok0 = blockIdx.x * 32;
  // 1. stage y (32x32 f32)
  if (t < 256) {
    *(float4*)&sy[t >> 3][(t & 7) * 4] =
        ((const float4*)(y + (size_t)tok0 * 32))[t];
  }
  __syncthreads();
  // 2. phase A MFMA: build y A-frags (hi/lo), Win B-frags from global
  f32x4 acc[2][2];
  {
    bf16x8 yah[2], yal[2];
    int k0 = (l >> 4) << 3;
    #pragma unroll
    for (int m = 0; m < 2; ++m) {
      int row = m * 16 + (l & 15);
      float4 f0 = *(float4*)&sy[row][k0];
      float4 f1 = *(float4*)&sy[row][k0 + 4];
      float v0 = f0.x, v1_ = f0.y, v2 = f0.z, v3 = f0.w;
      float v4 = f1.x, v5 = f1.y, v6 = f1.z, v7 = f1.w;
      unsigned short h0 = f2bf(v0), h1 = f2bf(v1_), h2 = f2bf(v2), h3 = f2bf(v3);
      unsigned short h4 = f2bf(v4), h5 = f2bf(v5), h6 = f2bf(v6), h7 = f2bf(v7);
      yah[m][0] = (short)h0; yah[m][1] = (short)h1; yah[m][2] = (short)h2; yah[m][3] = (short)h3;
      yah[m][4] = (short)h4; yah[m][5] = (short)h5; yah[m][6] = (short)h6; yah[m][7] = (short)h7;
      yal[m][0] = (short)f2bf(v0 - bf2f(h0)); yal[m][1] = (short)f2bf(v1_ - bf2f(h1));
      yal[m][2] = (short)f2bf(v2 - bf2f(h2)); yal[m][3] = (short)f2bf(v3 - bf2f(h3));
      yal[m][4] = (short)f2bf(v4 - bf2f(h4)); yal[m][5] = (short)f2bf(v5 - bf2f(h5));
      yal[m][6] = (short)f2bf(v6 - bf2f(h6)); yal[m][7] = (short)f2bf(v7 - bf2f(h7));
    }
    const bf16x8* Bh = (const bf16x8*)Winfh;
    const bf16x8* Bl = (const bf16x8*)Winfl;
    #pragma unroll
    for (int n = 0; n < 2; ++n) {
      int tt = w * 2 + n;
      bf16x8 bh = Bh[tt * 64 + l];
      bf16x8 bl = Bl[tt * 64 + l];
      #pragma unroll
      for (int m = 0; m < 2; ++m) {
        f32x4 a = {0.f, 0.f, 0.f, 0.f};
        a = __builtin_amdgcn_mfma_f32_16x16x32_bf16(yah[m], bh, a, 0, 0, 0);
        a = __builtin_amdgcn_mfma_f32_16x16x32_bf16(yal[m], bh, a, 0, 0, 0);
        a = __builtin_amdgcn_mfma_f32_16x16x32_bf16(yah[m], bl, a, 0, 0, 0);
        a = __builtin_amdgcn_mfma_f32_16x16x32_bf16(yal[m], bl, a, 0, 0, 0);
        acc[m][n] = a;
      }
    }
  }
  // bias add: lane's two cols
  int c0 = w * 32 + (l & 15), c1 = c0 + 16;
  {
    float b0 = bin_[c0], b1v = bin_[c1];
    #pragma unroll
    for (int m = 0; m < 2; ++m)
      #pragma unroll
      for (int r = 0; r < 4; ++r) { acc[m][0][r] += b0; acc[m][1][r] += b1v; }
  }
  // 3. LN partial reduce over this wave's 32 cols (16-lane groups)
  {
    #pragma unroll
    for (int m = 0; m < 2; ++m)
      #pragma unroll
      for (int r = 0; r < 4; ++r) {
        float a0 = acc[m][0][r], a1 = acc[m][1][r];
        float s1 = a0 + a1;
        float s2 = a0 * a0 + a1 * a1;
        #pragma unroll
        for (int off = 1; off < 16; off <<= 1) {
          s1 += __shfl_xor(s1, off);
          s2 += __shfl_xor(s2, off);
        }
        if ((l & 15) == 0) {
          int tok = m * 16 + ((l >> 4) << 2) + r;
          sred[tok][w * 2] = s1;
          sred[tok][w * 2 + 1] = s2;
        }
      }
  }
  __syncthreads();
  // 4. combine partials -> mu, rstd, sigma (threads 0..31)
  if (t < 32) {
    float s1 = 0.f, s2 = 0.f;
    #pragma unroll
    for (int q = 0; q < 8; ++q) { s1 += sred[t][q * 2]; s2 += sred[t][q * 2 + 1]; }
    float mu = s1 * (1.f / D);
    float var = s2 * (1.f / D) - mu * mu;
    float rstd = rsqrtf(var + 1e-5f);
    smu[t] = mu;
    srstd[t] = rstd;
    ssig[t] = sqrtf(var + 1e-5f);
  }
  __syncthreads();
  // 5. hn = LN(h) -> DIRECT bf16 hi/lo swizzled write; delta partial reduce
  {
    float g0 = ng[c0], g1 = ng[c1];
    float nb0 = nb[c0], nb1 = nb[c1];
    float q0 = qd[c0], q1 = qd[c1];
    float ddv[2][4];
    #pragma unroll
    for (int m = 0; m < 2; ++m)
      #pragma unroll
      for (int r = 0; r < 4; ++r) {
        int tok = m * 16 + ((l >> 4) << 2) + r;
        float mu = smu[tok], rstd = srstd[tok];
        float h0 = (acc[m][0][r] - mu) * rstd * g0 + nb0;
        float h1 = (acc[m][1][r] - mu) * rstd * g1 + nb1;
        unsigned swz = (unsigned)((tok & 7) << 4);
        unsigned base = (unsigned)tok * 512;
        unsigned short h0h = f2bf(h0);
        unsigned short h0l = f2bf(h0 - bf2f(h0h));
        unsigned short h1h = f2bf(h1);
        unsigned short h1l = f2bf(h1 - bf2f(h1h));
        *(unsigned short*)((char*)sChA_h + base + (((unsigned)(2 * c0)) ^ swz)) = h0h;
        *(unsigned short*)((char*)sChA_l + base + (((unsigned)(2 * c0)) ^ swz)) = h0l;
        *(unsigned short*)((char*)sChA_h + base + (((unsigned)(2 * c1)) ^ swz)) = h1h;
        *(unsigned short*)((char*)sChA_l + base + (((unsigned)(2 * c1)) ^ swz)) = h1l;
        float dx = h0 * q0 + h1 * q1;
        #pragma unroll
        for (int off = 1; off < 16; off <<= 1) dx += __shfl_xor(dx, off);
        ddv[m][r] = dx;
      }
    if ((l & 15) == 0) {
      #pragma unroll
      for (int m = 0; m < 2; ++m)
        #pragma unroll
        for (int r = 0; r < 4; ++r)
          sred[m * 16 + ((l >> 4) << 2) + r][w] = ddv[m][r];
    }
  }
  __syncthreads();
  // 6. delta combine + INCLUSIVE PREFIX (cds) + T (threads 0..31)
  if (t < 32) {
    float dsum = 0.f;
    #pragma unroll
    for (int q = 0; q < 8; ++q) dsum += sred[t][q];
    float xx = pd[0] + dsum;
    float dv = (xx > 20.f) ? xx : log1pf(expf(xx));
    sdelta[t] = dv;
    float c = dv;
    #pragma unroll
    for (int off = 1; off < 32; off <<= 1) {
      float o = __shfl_up(c, off);
      if (t >= off) c += o;
    }
    cdsg[tok0 + t] = c;
    if (t == 31) T[blockIdx.x] = c;
  }
  __syncthreads();
  // 7. phase C MFMA (waves 0-3): [Bm|Cm]; B,C -> LDS; Cm also -> global
  if (w < 4) {
    int mw = w & 1, nw = w >> 1;
    int row = mw * 16 + (l & 15);
    unsigned abase = (unsigned)row * 512;
    const bf16x8* B2h = (const bf16x8*)Wbcfh;
    const bf16x8* B2l = (const bf16x8*)Wbcfl;
    f32x4 acc2 = {0.f, 0.f, 0.f, 0.f};
    #pragma unroll
    for (int s = 0; s < 8; ++s) {
      unsigned off = ((unsigned)(s * 64 + ((l >> 4) << 4))) ^ ((unsigned)(row & 7) << 4);
      bf16x8 ah = *(const bf16x8*)((const char*)sChA_h + abase + off);
      bf16x8 al = *(const bf16x8*)((const char*)sChA_l + abase + off);
      int bi = (s * 2 + nw) * 64 + l;
      bf16x8 bh = B2h[bi];
      bf16x8 bl = B2l[bi];
      acc2 = __builtin_amdgcn_mfma_f32_16x16x32_bf16(ah, bh, acc2, 0, 0, 0);
      acc2 = __builtin_amdgcn_mfma_f32_16x16x32_bf16(al, bh, acc2, 0, 0, 0);
      acc2 = __builtin_amdgcn_mfma_f32_16x16x32_bf16(ah, bl, acc2, 0, 0, 0);
      acc2 = __builtin_amdgcn_mfma_f32_16x16x32_bf16(al, bl, acc2, 0, 0, 0);
    }
    int tokr = mw * 16 + ((l >> 4) << 2);
    int colc = l & 15;
    if (nw == 0) {
      #pragma unroll
      for (int r = 0; r < 4; ++r) sB[tokr + r][colc] = acc2[r];
    } else {
      #pragma unroll
      for (int r = 0; r < 4; ++r) {
        Cm[(size_t)(tok0 + tokr + r) * NX + colc] = acc2[r];
        sC[tokr + r][colc] = acc2[r];
      }
    }
  }
  __syncthreads();
  // 8. scan: ALL 8 waves; 8-n halves; hn reconstructed from sChA hi+lo.
  // half 0 -> vpart0 = h + p(n<8); half 1 -> vpart1 = p(n>=8).
  {
    int half = t >> 8;          // wave-uniform
    int d = t & 255;
    float a8[8], x8[8];
    #pragma unroll
    for (int n = 0; n < 8; ++n) {
      a8[n] = At[(half * 8 + n) * D + d];
      x8[n] = 0.f;
    }
    float nb_d = nb[d];
    float invg = 1.0f / ng[d];
    float* vout = (half ? vpart1 : vpart0) + (size_t)tok0 * D + d;
    for (int lo = 0; lo < CL; ++lo) {
      unsigned hoff = ((unsigned)(2 * d)) ^ ((unsigned)((lo & 7) << 4));
      float hn_v = bf2f(*(unsigned short*)((char*)sChA_h + lo * 512 + hoff)) +
                   bf2f(*(unsigned short*)((char*)sChA_l + lo * 512 + hoff));
      float dlt = sdelta[lo];
      float du = dlt * hn_v;
      float Bv[8], Cvv[8];
      *(float4*)&Bv[0] = *(float4*)&sB[lo][half * 8];
      *(float4*)&Bv[4] = *(float4*)&sB[lo][half * 8 + 4];
      *(float4*)&Cvv[0] = *(float4*)&sC[lo][half * 8];
      *(float4*)&Cvv[4] = *(float4*)&sC[lo][half * 8 + 4];
      float p = 0.f;
      #pragma unroll
      for (int n = 0; n < 8; ++n) {
        x8[n] = fmaf(exp2f(dlt * a8[n]), x8[n], du * Bv[n]);
        p = fmaf(x8[n], Cvv[n], p);
      }
      float v;
      if (half == 0) {
        float h = fmaf((hn_v - nb_d) * invg, ssig[lo], smu[lo]);
        v = h + p;
      } else {
        v = p;
      }
      vout[(size_t)lo * D] = v;
    }
    size_t exbase = (size_t)blockIdx.x * (NX * D) + d;
    #pragma unroll
    for (int n = 0; n < 8; ++n) EX[exbase + (half * 8 + n) * D] = x8[n];
  }
}

// ---------------- K2b: chunk-level scan, 8-deep prefetch ring --------------
__global__ __launch_bounds__(64) void k2b_chunkscan(
    const float* __restrict__ At, const float* __restrict__ T,
    float* __restrict__ EX) {
  __shared__ float sT[NCH];
  int b = blockIdx.x >> 6;
  int rem = ((blockIdx.x & 63) << 6) | threadIdx.x;  // n*D + d
  sT[threadIdx.x] = T[b * NCH + threadIdx.x];
  __syncthreads();
  float A2 = At[rem];  // already *LOG2E
  size_t base = ((size_t)b << 18) + rem;
  float eq[8];
  #pragma unroll
  for (int j = 0; j < 8; ++j) eq[j] = EX[base + ((size_t)j << 12)];
  float x = 0.f;
  #pragma unroll 8
  for (int c = 0; c < NCH; ++c) {
    float e = eq[c & 7];
    if (c + 8 < NCH) eq[c & 7] = EX[base + ((size_t)(c + 8) << 12)];
    EX[base + ((size_t)c << 12)] = x;
    x = fmaf(exp2f(sT[c] * A2), x, e);
  }
}

__device__ __forceinline__ float gelu_exact(float x) {
  return 0.5f * x * (1.f + erff(x * 0.70710678118654752440f));
}

// ---------------- K2cd: PARALLEL FIXUP + LN2-FOLDED MFMA MLP, 512 thr -------
// r10 + vp read sums the two vpart planes.
__global__ __launch_bounds__(512, 4) void k2cd_scan_mlp(
    const float* __restrict__ vpart0, const float* __restrict__ vpart1,
    const float* __restrict__ cdsg, const float* __restrict__ Cm,
    const float* __restrict__ At, const float* __restrict__ EX,
    const unsigned short* __restrict__ W1fh, const unsigned short* __restrict__ W1fl,
    const unsigned short* __restrict__ W2fh, const unsigned short* __restrict__ W2fl,
    const float* __restrict__ u1, const float* __restrict__ v1,
    const float* __restrict__ b1, const float* __restrict__ b2,
    float* __restrict__ out) {
  __shared__ __align__(16) unsigned short sAh[32 * 256]; // bf16 hi (x-tile, then z)
  __shared__ __align__(16) unsigned short sAl[32 * 256]; // bf16 lo
  __shared__ float srstd2[32];
  __shared__ float smur2[32];      // mu*rstd per token
  int t = threadIdx.x;
  int l = t & 63, w = t >> 6;
  int tok0 = blockIdx.x * 32;  // blockIdx.x == global chunk index
  size_t tokbase = (size_t)tok0;
  // ---- parallel fixup: thread (g, d) handles tokens g*16 .. g*16+15 ----
  {
    int g = t >> 8, d = t & 255;
    float a16v[16], xe[16];
    size_t exbase = (size_t)blockIdx.x * (NX * D) + d;
    #pragma unroll
    for (int n = 0; n < 16; ++n) {
      a16v[n] = At[n * D + d];
      xe[n] = EX[exbase + n * D];
    }
    const float* vp0_base = vpart0 + (tokbase + g * 16) * D + d;
    const float* vp1_base = vpart1 + (tokbase + g * 16) * D + d;
    #pragma unroll 4
    for (int q = 0; q < 16; ++q) {
      int tok = g * 16 + q;
      float vp = vp0_base[(size_t)q * D] + vp1_base[(size_t)q * D];
      float ct = cdsg[tokbase + tok];           // uniform -> s_load
      float pf = 0.f;
      #pragma unroll
      for (int n = 0; n < 16; ++n) {
        float cv = Cm[(tokbase + tok) * NX + n];  // uniform -> s_load
        pf = fmaf(cv * exp2f(ct * a16v[n]), xe[n], pf);
      }
      float v = vp + pf;  // final pre-LN2 value, token tok, column d
      unsigned short vh = f2bf(v);
      unsigned short vl = f2bf(v - bf2f(vh));
      unsigned off16 = ((unsigned)(d * 2)) ^ ((unsigned)((tok & 7) << 4));
      *(unsigned short*)((char*)sAh + tok * 512 + off16) = vh;
      *(unsigned short*)((char*)sAl + tok * 512 + off16) = vl;
    }
  }
  __syncthreads();
  // stats phase: wave w handles tokens w*4..w*4+3; 64 lanes x 4 cols each
  {
    #pragma unroll
    for (int p = 0; p < 4; ++p) {
      int tok = w * 4 + p;
      unsigned off = ((unsigned)(l * 8)) ^ ((unsigned)((tok & 7) << 4));
      uint2 hv2 = *(uint2*)((char*)sAh + tok * 512 + off);
      uint2 lv2 = *(uint2*)((char*)sAl + tok * 512 + off);
      float v0 = bf2f((unsigned short)(hv2.x & 0xffff)) + bf2f((unsigned short)(lv2.x & 0xffff));
      float v1_ = bf2f((unsigned short)(hv2.x >> 16)) + bf2f((unsigned short)(lv2.x >> 16));
      float v2 = bf2f((unsigned short)(hv2.y & 0xffff)) + bf2f((unsigned short)(lv2.y & 0xffff));
      float v3 = bf2f((unsigned short)(hv2.y >> 16)) + bf2f((unsigned short)(lv2.y >> 16));
      float s1 = v0 + v1_ + v2 + v3;
      float s2 = v0 * v0 + v1_ * v1_ + v2 * v2 + v3 * v3;
      #pragma unroll
      for (int off2 = 1; off2 < 64; off2 <<= 1) {
        s1 += __shfl_xor(s1, off2);
        s2 += __shfl_xor(s2, off2);
      }
      if (l == 0) {
        float mu = s1 * (1.f / D);
        float var = s2 * (1.f / D) - mu * mu;
        float rstd = rsqrtf(var + 1e-5f);
        srstd2[tok] = rstd;
        smur2[tok] = mu * rstd;
      }
    }
  }
  __syncthreads();
  // ---- GEMM1: x (32x256) @ W1g (256x256); wave w owns cols [w*32,+32) ----
  const bf16x8* B1h = (const bf16x8*)W1fh;
  const bf16x8* B1l = (const bf16x8*)W1fl;
  f32x4 acc[2][2];
  #pragma unroll
  for (int m = 0; m < 2; ++m)
    #pragma unroll
    for (int n = 0; n < 2; ++n) {
      f32x4 z4 = {0.f, 0.f, 0.f, 0.f};
      acc[m][n] = z4;
    }
  #pragma unroll 2
  for (int s = 0; s < 8; ++s) {
    bf16x8 ah[2], al[2];
    #pragma unroll
    for (int m = 0; m < 2; ++m) {
      int row = m * 16 + (l & 15);
      unsigned off16 = ((unsigned)(s * 64 + ((l >> 4) << 4))) ^ ((unsigned)(row & 7) << 4);
      ah[m] = *(const bf16x8*)((const char*)sAh + row * 512 + off16);
      al[m] = *(const bf16x8*)((const char*)sAl + row * 512 + off16);
    }
    #pragma unroll
    for (int n = 0; n < 2; ++n) {
      int bi = (s * 16 + w * 2 + n) * 64 + l;
      bf16x8 bh = B1h[bi];
      bf16x8 bl = B1l[bi];
      #pragma unroll
      for (int m = 0; m < 2; ++m) {
        acc[m][n] = __builtin_amdgcn_mfma_f32_16x16x32_bf16(ah[m], bh, acc[m][n], 0, 0, 0);
        acc[m][n] = __builtin_amdgcn_mfma_f32_16x16x32_bf16(al[m], bh, acc[m][n], 0, 0, 0);
        acc[m][n] = __builtin_amdgcn_mfma_f32_16x16x32_bf16(ah[m], bl, acc[m][n], 0, 0, 0);
        acc[m][n] = __builtin_amdgcn_mfma_f32_16x16x32_bf16(al[m], bl, acc[m][n], 0, 0, 0);
      }
    }
  }
  __syncthreads();  // all A-tile reads done; sAh/sAl now reused for z
  // ---- LN2 affine + b1 + gelu -> z (bf16 hi/lo) back into sAh/sAl ----
  #pragma unroll
  for (int n = 0; n < 2; ++n) {
    int colz = w * 32 + n * 16 + (l & 15);
    float u1c = u1[colz];
    float v1c = v1[colz] + b1[colz];
    #pragma unroll
    for (int m = 0; m < 2; ++m) {
      #pragma unroll
      for (int r = 0; r < 4; ++r) {
        int row = m * 16 + ((l >> 4) << 2) + r;  // C/D: row=(lane>>4)*4+reg
        float zpre = acc[m][n][r] * srstd2[row] - smur2[row] * u1c + v1c;
        float zv = gelu_exact(zpre);
        unsigned short zh = f2bf(zv);
        unsigned short zl = f2bf(zv - bf2f(zh));
        unsigned off16 = ((unsigned)(colz * 2)) ^ ((unsigned)(row & 7) << 4);
        *(unsigned short*)((char*)sAh + row * 512 + off16) = zh;
        *(unsigned short*)((char*)sAl + row * 512 + off16) = zl;
      }
    }
  }
  __syncthreads();
  // ---- GEMM2: z (32x256) @ W2 (256x32); waves 0-3 -> (mw=w>>1, nw=w&1) ----
  if (w < 4) {
    int mw = w >> 1, nw = w & 1;
    const bf16x8* B2h = (const bf16x8*)W2fh;
    const bf16x8* B2l = (const bf16x8*)W2fl;
    f32x4 acc2 = {0.f, 0.f, 0.f, 0.f};
    #pragma unroll 2
    for (int s = 0; s < 8; ++s) {
      int row = mw * 16 + (l & 15);
      unsigned off16 = ((unsigned)(s * 64 + ((l >> 4) << 4))) ^ ((unsigned)(row & 7) << 4);
      bf16x8 zh8 = *(const bf16x8*)((const char*)sAh + row * 512 + off16);
      bf16x8 zl8 = *(const bf16x8*)((const char*)sAl + row * 512 + off16);
      int bi = (s * 2 + nw) * 64 + l;
      bf16x8 bh = B2h[bi];
      bf16x8 bl = B2l[bi];
      acc2 = __builtin_amdgcn_mfma_f32_16x16x32_bf16(zh8, bh, acc2, 0, 0, 0);
      acc2 = __builtin_amdgcn_mfma_f32_16x16x32_bf16(zl8, bh, acc2, 0, 0, 0);
      acc2 = __builtin_amdgcn_mfma_f32_16x16x32_bf16(zh8, bl, acc2, 0, 0, 0);
      acc2 = __builtin_amdgcn_mfma_f32_16x16x32_bf16(zl8, bl, acc2, 0, 0, 0);
    }
    int colo = nw * 16 + (l & 15);
    float b2v = b2[colo];
    #pragma unroll
    for (int r = 0; r < 4; ++r) {
      int row = mw * 16 + ((l >> 4) << 2) + r;
      out[(size_t)(tok0 + row) * 32 + colo] = acc2[r] + b2v;
    }
  }
}

extern "C" void kernel_launch(void* const* d_in, const int* in_sizes, int n_in,
                              void* d_out, int out_size, void* d_ws, size_t ws_size,
                              hipStream_t stream) {
  const float* y    = (const float*)d_in[0];
  const float* Win  = (const float*)d_in[1];
  const float* bin_ = (const float*)d_in[2];
  const float* ng   = (const float*)d_in[3];
  const float* nb   = (const float*)d_in[4];
  const float* A    = (const float*)d_in[5];
  const float* WB   = (const float*)d_in[6];
  const float* WC   = (const float*)d_in[7];
  const float* qd   = (const float*)d_in[8];
  const float* pd   = (const float*)d_in[9];
  const float* nfg  = (const float*)d_in[10];
  const float* nfb  = (const float*)d_in[11];
  const float* W1   = (const float*)d_in[12];
  const float* b1   = (const float*)d_in[13];
  const float* W2   = (const float*)d_in[14];
  const float* b2   = (const float*)d_in[15];

  float* ws = (float*)d_ws;
  float* vpart0 = ws;                         // NTOK*D (h + p_local n<8)
  float* vpart1 = ws + 4194304;               // NTOK*D (p_local n>=8)
  float* cdsg  = vpart1 + 4194304;            // NTOK (inclusive delta prefix)
  float* Cm    = cdsg + NTOK;                 // NTOK*NX
  float* Tbuf  = Cm + NTOK * NX;              // 512
  float* At    = Tbuf + NBATCH * NCH;         // 4096
  float* EX    = At + D * NX;                 // 512*4096 = 2M floats
  // bf16 fragment-packed weights (hi/lo)
  unsigned short* W1fh  = (unsigned short*)(EX + 2097152);  // 65536
  unsigned short* W1fl  = W1fh + 65536;                     // 65536
  unsigned short* W2fh  = W1fl + 65536;                     // 8192
  unsigned short* W2fl  = W2fh + 8192;                      // 8192
  unsigned short* Winfh = W2fl + 8192;                      // 8192
  unsigned short* Winfl = Winfh + 8192;                     // 8192
  unsigned short* Wbcfh = Winfl + 8192;                     // 8192
  unsigned short* Wbcfl = Wbcfh + 8192;                     // 8192
  float* u1 = (float*)(Wbcfl + 8192);                       // 256
  float* v1 = u1 + 256;                                     // 256

  k0_prep<<<370, 256, 0, stream>>>(A, WB, WC, Win, W1, W2, nfg, nfb, At,
                                   W1fh, W1fl, W2fh, W2fl,
                                   Winfh, Winfl, Wbcfh, Wbcfl, u1, v1);
  k1a_front_scan<<<NTOK / 32, 512, 0, stream>>>(y, bin_, ng, nb, qd, pd, At,
                                                Winfh, Winfl, Wbcfh, Wbcfl,
                                                vpart0, vpart1, cdsg, Cm,
                                                EX, Tbuf);
  k2b_chunkscan<<<NBATCH * 64, 64, 0, stream>>>(At, Tbuf, EX);
  k2cd_scan_mlp<<<NTOK / 32, 512, 0, stream>>>(vpart0, vpart1, cdsg, Cm,
                                               At, EX,
                                               W1fh, W1fl, W2fh, W2fl,
                                               u1, v1, b1, b2, (float*)d_out);
}

// Round 12
// 185.292 us; speedup vs baseline: 1.0498x; 1.0363x over previous
//
#include <hip/hip_runtime.h>
#include <math.h>

#define D 256
#define NX 16
#define L 2048
#define NBATCH 8
#define NTOK (NBATCH * L)
#define CL 32
#define NCH (L / CL)  // 64
#define LOG2E 1.44269504088896340736f

typedef float f32x4 __attribute__((ext_vector_type(4)));
// Fragment type for mfma_f32_16x16x32_bf16 on gfx950: 8 bf16 as 8 shorts.
typedef short bf16x8 __attribute__((ext_vector_type(8)));

// round-to-nearest-even f32 -> bf16 (as ushort bits)
__device__ __forceinline__ unsigned short f2bf(float x) {
  unsigned u = __float_as_uint(x);
  u = u + 0x7fffu + ((u >> 16) & 1u);
  return (unsigned short)(u >> 16);
}
__device__ __forceinline__ float bf2f(unsigned short h) {
  return __uint_as_float(((unsigned)h) << 16);
}

// ---------------- K0: At prep + ALL weight fragment packing (hi/lo bf16) ----
// Fragment K-enumeration shared by A and B operands: element j of lane l
// covers k = s*32 + 8*(l>>4) + j; 16-dim = lane&15. Valid for any HW k-map.
__global__ __launch_bounds__(256) void k0_prep(const float* __restrict__ A,
                                               const float* __restrict__ WB,
                                               const float* __restrict__ WC,
                                               const float* __restrict__ Win,
                                               const float* __restrict__ W1,
                                               const float* __restrict__ W2,
                                               float* __restrict__ At,
                                               unsigned short* __restrict__ W1fh,
                                               unsigned short* __restrict__ W1fl,
                                               unsigned short* __restrict__ W2fh,
                                               unsigned short* __restrict__ W2fl,
                                               unsigned short* __restrict__ Winfh,
                                               unsigned short* __restrict__ Winfl,
                                               unsigned short* __restrict__ Wbcfh,
                                               unsigned short* __restrict__ Wbcfl) {
  int i = blockIdx.x * 256 + threadIdx.x;  // 94208 total
  if (i < 4096) {
    int d = i >> 4, n = i & 15;
    At[n * D + d] = A[i] * LOG2E;
  } else if (i < 12288) {
    // Win frags (B of phase A, K=32): e = (tt*64 + l)*8 + j, tt=0..15
    int e = i - 4096;
    int j = e & 7, l = (e >> 3) & 63, tt = e >> 9;
    int k = ((l >> 4) << 3) + j;        // K=32, single K-step
    int n = tt * 16 + (l & 15);
    float x = Win[k * 256 + n];
    unsigned short h = f2bf(x);
    Winfh[e] = h;
    Winfl[e] = f2bf(x - bf2f(h));
  } else if (i < 20480) {
    // Wbct frags (B of phase C): e = ((s*2+tt)*64 + l)*8 + j
    int e = i - 12288;
    int j = e & 7, l = (e >> 3) & 63, q = e >> 9;  // q = s*2+tt
    int s = q >> 1, tt = q & 1;
    int k = s * 32 + ((l >> 4) << 3) + j;
    int n = tt * 16 + (l & 15);
    float x = (n < 16) ? WB[n * 256 + k] : WC[(n - 16) * 256 + k];
    unsigned short h = f2bf(x);
    Wbcfh[e] = h;
    Wbcfl[e] = f2bf(x - bf2f(h));
  } else if (i < 86016) {
    // W1 frags: e = ((s*16 + t)*64 + l)*8 + j ; 65536 elems
    int e = i - 20480;
    int j = e & 7, l = (e >> 3) & 63, tt = (e >> 9) & 15, s = e >> 13;
    int k = s * 32 + ((l >> 4) << 3) + j;
    int n = tt * 16 + (l & 15);
    float x = W1[k * 256 + n];
    unsigned short h = f2bf(x);
    W1fh[e] = h;
    W1fl[e] = f2bf(x - bf2f(h));
  } else {
    // W2 frags: e = ((s*2 + t)*64 + l)*8 + j ; 8192 elems
    int e = i - 86016;
    int j = e & 7, l = (e >> 3) & 63, tt = (e >> 9) & 1, s = e >> 10;
    int k = s * 32 + ((l >> 4) << 3) + j;
    int n = tt * 16 + (l & 15);
    float x = W2[k * 32 + n];
    unsigned short h = f2bf(x);
    W2fh[e] = h;
    W2fl[e] = f2bf(x - bf2f(h));
  }
}

// ---------------- K1A: MFMA front end + LOCAL CHUNK SCAN, 512 thr ----------
// Round-6 (182 µs) version + float4 sB reads in the scan (LDS-pipe relief).
__global__ __launch_bounds__(512, 4) void k1a_front_scan(
    const float* __restrict__ y, const float* __restrict__ bin_,
    const float* __restrict__ ng, const float* __restrict__ nb,
    const float* __restrict__ qd, const float* __restrict__ pd,
    const float* __restrict__ At,
    const unsigned short* __restrict__ Winfh,
    const unsigned short* __restrict__ Winfl,
    const unsigned short* __restrict__ Wbcfh,
    const unsigned short* __restrict__ Wbcfl,
    float* __restrict__ hn, float* __restrict__ delta,
    float* __restrict__ Bm, float* __restrict__ Cm,
    float* __restrict__ muv, float* __restrict__ irsv,
    float* __restrict__ EX, float* __restrict__ T) {
  __shared__ float sy[32][36];       // y tile, padded pitch (bank spread)
  __shared__ float sh[32][260];      // hn tile f32, pitch 260
  __shared__ float sB[32][NX];
  __shared__ float sred[32][16];     // per-wave LN/delta partials
  __shared__ float sdelta[32];
  __shared__ float smu[32];
  __shared__ float srstd[32];
  __shared__ __align__(16) unsigned short sChA_h[32 * 256];  // hn bf16 hi (swz)
  __shared__ __align__(16) unsigned short sChA_l[32 * 256];  // hn bf16 lo (swz)
  int t = threadIdx.x;
  int l = t & 63;
  int w = t >> 6;
  int tok0 = blockIdx.x * 32;
  // 1. stage y (32x32 f32)
  if (t < 256) {
    int row = t >> 3, c4 = t & 7;
    *(float4*)&sy[row][c4 * 4] = ((const float4*)(y + (size_t)tok0 * 32))[t];
  }
  __syncthreads();
  // 2. phase A MFMA: build y A-frags (hi/lo), Win B-frags from global
  f32x4 acc[2][2];
  {
    bf16x8 yah[2], yal[2];
    int k0 = (l >> 4) << 3;
    #pragma unroll
    for (int m = 0; m < 2; ++m) {
      int row = m * 16 + (l & 15);
      float4 f0 = *(float4*)&sy[row][k0];
      float4 f1 = *(float4*)&sy[row][k0 + 4];
      float v0 = f0.x, v1_ = f0.y, v2 = f0.z, v3 = f0.w;
      float v4 = f1.x, v5 = f1.y, v6 = f1.z, v7 = f1.w;
      unsigned short h0 = f2bf(v0), h1 = f2bf(v1_), h2 = f2bf(v2), h3 = f2bf(v3);
      unsigned short h4 = f2bf(v4), h5 = f2bf(v5), h6 = f2bf(v6), h7 = f2bf(v7);
      yah[m][0] = (short)h0; yah[m][1] = (short)h1; yah[m][2] = (short)h2; yah[m][3] = (short)h3;
      yah[m][4] = (short)h4; yah[m][5] = (short)h5; yah[m][6] = (short)h6; yah[m][7] = (short)h7;
      yal[m][0] = (short)f2bf(v0 - bf2f(h0)); yal[m][1] = (short)f2bf(v1_ - bf2f(h1));
      yal[m][2] = (short)f2bf(v2 - bf2f(h2)); yal[m][3] = (short)f2bf(v3 - bf2f(h3));
      yal[m][4] = (short)f2bf(v4 - bf2f(h4)); yal[m][5] = (short)f2bf(v5 - bf2f(h5));
      yal[m][6] = (short)f2bf(v6 - bf2f(h6)); yal[m][7] = (short)f2bf(v7 - bf2f(h7));
    }
    const bf16x8* Bh = (const bf16x8*)Winfh;
    const bf16x8* Bl = (const bf16x8*)Winfl;
    #pragma unroll
    for (int n = 0; n < 2; ++n) {
      int tt = w * 2 + n;
      bf16x8 bh = Bh[tt * 64 + l];
      bf16x8 bl = Bl[tt * 64 + l];
      #pragma unroll
      for (int m = 0; m < 2; ++m) {
        f32x4 a = {0.f, 0.f, 0.f, 0.f};
        a = __builtin_amdgcn_mfma_f32_16x16x32_bf16(yah[m], bh, a, 0, 0, 0);
        a = __builtin_amdgcn_mfma_f32_16x16x32_bf16(yal[m], bh, a, 0, 0, 0);
        a = __builtin_amdgcn_mfma_f32_16x16x32_bf16(yah[m], bl, a, 0, 0, 0);
        a = __builtin_amdgcn_mfma_f32_16x16x32_bf16(yal[m], bl, a, 0, 0, 0);
        acc[m][n] = a;
      }
    }
  }
  // bias add: lane's two cols
  int c0 = w * 32 + (l & 15), c1 = c0 + 16;
  {
    float b0 = bin_[c0], b1v = bin_[c1];
    #pragma unroll
    for (int m = 0; m < 2; ++m)
      #pragma unroll
      for (int r = 0; r < 4; ++r) { acc[m][0][r] += b0; acc[m][1][r] += b1v; }
  }
  // 3. LN partial reduce over this wave's 32 cols (16-lane groups)
  {
    #pragma unroll
    for (int m = 0; m < 2; ++m)
      #pragma unroll
      for (int r = 0; r < 4; ++r) {
        float a0 = acc[m][0][r], a1 = acc[m][1][r];
        float s1 = a0 + a1;
        float s2 = a0 * a0 + a1 * a1;
        #pragma unroll
        for (int off = 1; off < 16; off <<= 1) {
          s1 += __shfl_xor(s1, off);
          s2 += __shfl_xor(s2, off);
        }
        if ((l & 15) == 0) {
          int tok = m * 16 + ((l >> 4) << 2) + r;
          sred[tok][w * 2] = s1;
          sred[tok][w * 2 + 1] = s2;
        }
      }
  }
  __syncthreads();
  // 4. combine partials -> mu, rstd (threads 0..31)
  if (t < 32) {
    float s1 = 0.f, s2 = 0.f;
    #pragma unroll
    for (int q = 0; q < 8; ++q) { s1 += sred[t][q * 2]; s2 += sred[t][q * 2 + 1]; }
    float mu = s1 * (1.f / D);
    float var = s2 * (1.f / D) - mu * mu;
    float rstd = rsqrtf(var + 1e-5f);
    smu[t] = mu;
    srstd[t] = rstd;
    muv[tok0 + t] = mu;
    irsv[tok0 + t] = sqrtf(var + 1e-5f);
  }
  __syncthreads();
  // 5. hn = LN(h); write sh f32; delta partial reduce
  {
    float g0 = ng[c0], g1 = ng[c1];
    float nb0 = nb[c0], nb1 = nb[c1];
    float q0 = qd[c0], q1 = qd[c1];
    float ddv[2][4];
    #pragma unroll
    for (int m = 0; m < 2; ++m)
      #pragma unroll
      for (int r = 0; r < 4; ++r) {
        int tok = m * 16 + ((l >> 4) << 2) + r;
        float mu = smu[tok], rstd = srstd[tok];
        float h0 = (acc[m][0][r] - mu) * rstd * g0 + nb0;
        float h1 = (acc[m][1][r] - mu) * rstd * g1 + nb1;
        sh[tok][c0] = h0;
        sh[tok][c1] = h1;
        float dx = h0 * q0 + h1 * q1;
        #pragma unroll
        for (int off = 1; off < 16; off <<= 1) dx += __shfl_xor(dx, off);
        ddv[m][r] = dx;
      }
    if ((l & 15) == 0) {
      #pragma unroll
      for (int m = 0; m < 2; ++m)
        #pragma unroll
        for (int r = 0; r < 4; ++r)
          sred[m * 16 + ((l >> 4) << 2) + r][w] = ddv[m][r];
    }
  }
  __syncthreads();
  // 6. delta combine + T (t<32) ; all threads: sh -> bf16 hi/lo swizzled
  if (t < 32) {
    float dsum = 0.f;
    #pragma unroll
    for (int q = 0; q < 8; ++q) dsum += sred[t][q];
    float xx = pd[0] + dsum;
    float dv = (xx > 20.f) ? xx : log1pf(expf(xx));
    delta[tok0 + t] = dv;
    sdelta[t] = dv;
    float tv = dv;
    #pragma unroll
    for (int off = 1; off < 32; off <<= 1) tv += __shfl_xor(tv, off);
    if (t == 0) T[blockIdx.x] = tv;
  }
  {
    int row = t & 31;
    int cq = (t >> 5) * 16;   // 16 cols per thread
    float4 f0 = *(float4*)&sh[row][cq];
    float4 f1 = *(float4*)&sh[row][cq + 4];
    float4 f2 = *(float4*)&sh[row][cq + 8];
    float4 f3 = *(float4*)&sh[row][cq + 12];
    float vv[16] = {f0.x, f0.y, f0.z, f0.w, f1.x, f1.y, f1.z, f1.w,
                    f2.x, f2.y, f2.z, f2.w, f3.x, f3.y, f3.z, f3.w};
    unsigned hw[8], lw[8];
    #pragma unroll
    for (int p = 0; p < 8; ++p) {
      unsigned short ha = f2bf(vv[2 * p]), hb = f2bf(vv[2 * p + 1]);
      unsigned short la = f2bf(vv[2 * p] - bf2f(ha));
      unsigned short lb = f2bf(vv[2 * p + 1] - bf2f(hb));
      hw[p] = (unsigned)ha | ((unsigned)hb << 16);
      lw[p] = (unsigned)la | ((unsigned)lb << 16);
    }
    unsigned base = (unsigned)row * 512;
    #pragma unroll
    for (int g = 0; g < 2; ++g) {
      unsigned off = ((unsigned)(cq * 2 + g * 16)) ^ ((unsigned)(row & 7) << 4);
      uint4 hv4 = {hw[g * 4], hw[g * 4 + 1], hw[g * 4 + 2], hw[g * 4 + 3]};
      uint4 lv4 = {lw[g * 4], lw[g * 4 + 1], lw[g * 4 + 2], lw[g * 4 + 3]};
      *(uint4*)((char*)sChA_h + base + off) = hv4;
      *(uint4*)((char*)sChA_l + base + off) = lv4;
    }
  }
  __syncthreads();
  // 7. phase C MFMA (waves 0-3); waves 4-7: hn -> global copy (coalesced)
  if (w < 4) {
    int mw = w & 1, nw = w >> 1;
    int row = mw * 16 + (l & 15);
    unsigned abase = (unsigned)row * 512;
    const bf16x8* B2h = (const bf16x8*)Wbcfh;
    const bf16x8* B2l = (const bf16x8*)Wbcfl;
    f32x4 acc2 = {0.f, 0.f, 0.f, 0.f};
    #pragma unroll
    for (int s = 0; s < 8; ++s) {
      unsigned off = ((unsigned)(s * 64 + ((l >> 4) << 4))) ^ ((unsigned)(row & 7) << 4);
      bf16x8 ah = *(const bf16x8*)((const char*)sChA_h + abase + off);
      bf16x8 al = *(const bf16x8*)((const char*)sChA_l + abase + off);
      int bi = (s * 2 + nw) * 64 + l;
      bf16x8 bh = B2h[bi];
      bf16x8 bl = B2l[bi];
      acc2 = __builtin_amdgcn_mfma_f32_16x16x32_bf16(ah, bh, acc2, 0, 0, 0);
      acc2 = __builtin_amdgcn_mfma_f32_16x16x32_bf16(al, bh, acc2, 0, 0, 0);
      acc2 = __builtin_amdgcn_mfma_f32_16x16x32_bf16(ah, bl, acc2, 0, 0, 0);
      acc2 = __builtin_amdgcn_mfma_f32_16x16x32_bf16(al, bl, acc2, 0, 0, 0);
    }
    int tokr = mw * 16 + ((l >> 4) << 2);
    int colc = l & 15;
    if (nw == 0) {
      #pragma unroll
      for (int r = 0; r < 4; ++r) {
        Bm[(size_t)(tok0 + tokr + r) * NX + colc] = acc2[r];
        sB[tokr + r][colc] = acc2[r];
      }
    } else {
      #pragma unroll
      for (int r = 0; r < 4; ++r)
        Cm[(size_t)(tok0 + tokr + r) * NX + colc] = acc2[r];
    }
  } else {
    float4* dst = (float4*)(hn + (size_t)tok0 * D);
    for (int i = t - 256; i < 2048; i += 256) {
      int row = i >> 6, c4 = i & 63;
      dst[i] = *(float4*)&sh[row][c4 * 4];
    }
  }
  __syncthreads();
  // 8. scan: n-split halves; thread = (half, d), x8 in regs; B via float4.
  {
    int half = t >> 8;          // 0: n=0..7, 1: n=8..15
    int d = t & 255;
    float a8[8], x8[8];
    #pragma unroll
    for (int n = 0; n < 8; ++n) {
      a8[n] = At[(half * 8 + n) * D + d];
      x8[n] = 0.f;
    }
    for (int lo = 0; lo < CL; ++lo) {
      float dlt = sdelta[lo];
      float du = dlt * sh[lo][d];
      float Bv[8];
      *(float4*)&Bv[0] = *(float4*)&sB[lo][half * 8];
      *(float4*)&Bv[4] = *(float4*)&sB[lo][half * 8 + 4];
      #pragma unroll
      for (int n = 0; n < 8; ++n)
        x8[n] = fmaf(exp2f(dlt * a8[n]), x8[n], du * Bv[n]);
    }
    size_t exbase = (size_t)blockIdx.x * (NX * D) + d;
    #pragma unroll
    for (int n = 0; n < 8; ++n) EX[exbase + (half * 8 + n) * D] = x8[n];
  }
}

// ---------------- K2b: chunk-level scan, 8-deep prefetch ring --------------
__global__ __launch_bounds__(64) void k2b_chunkscan(
    const float* __restrict__ At, const float* __restrict__ T,
    float* __restrict__ EX) {
  __shared__ float sT[NCH];
  int b = blockIdx.x >> 6;
  int rem = ((blockIdx.x & 63) << 6) | threadIdx.x;  // n*D + d
  sT[threadIdx.x] = T[b * NCH + threadIdx.x];
  __syncthreads();
  float A2 = At[rem];  // already *LOG2E
  size_t base = ((size_t)b << 18) + rem;
  float eq[8];
  #pragma unroll
  for (int j = 0; j < 8; ++j) eq[j] = EX[base + ((size_t)j << 12)];
  float x = 0.f;
  #pragma unroll 8
  for (int c = 0; c < NCH; ++c) {
    float e = eq[c & 7];
    if (c + 8 < NCH) eq[c & 7] = EX[base + ((size_t)(c + 8) << 12)];
    EX[base + ((size_t)c << 12)] = x;
    x = fmaf(exp2f(sT[c] * A2), x, e);
  }
}

__device__ __forceinline__ float gelu_exact(float x) {
  return 0.5f * x * (1.f + erff(x * 0.70710678118654752440f));
}

// ---------------- K2cd: fixup scan + h recon + LN2 + MFMA MLP ---------------
// Round-6 (182 µs) version + float4 sB/sC reads + 1-ahead hn prefetch.
__global__ __launch_bounds__(256) void k2cd_scan_mlp(
    const float* __restrict__ hn, const float* __restrict__ delta,
    const float* __restrict__ Bm, const float* __restrict__ Cm,
    const float* __restrict__ At, const float* __restrict__ EX,
    const float* __restrict__ muv, const float* __restrict__ irsv,
    const float* __restrict__ ng, const float* __restrict__ nb,
    const float* __restrict__ nfg, const float* __restrict__ nfb,
    const unsigned short* __restrict__ W1fh, const unsigned short* __restrict__ W1fl,
    const unsigned short* __restrict__ W2fh, const unsigned short* __restrict__ W2fl,
    const float* __restrict__ b1, const float* __restrict__ b2,
    float* __restrict__ out) {
  __shared__ float s_az[32 * 260];                       // scan output (pre-LN2)
  __shared__ __align__(16) unsigned short sAh[32 * 256]; // bf16 hi (a-tile, then z)
  __shared__ __align__(16) unsigned short sAl[32 * 256]; // bf16 lo
  __shared__ float sB[32][NX];
  __shared__ float sC[32][NX];
  __shared__ float sdelta[32];
  __shared__ float smu[32];
  __shared__ float sirs[32];
  int t = threadIdx.x;
  int tok0 = blockIdx.x * 32;  // blockIdx.x == global chunk index
  size_t tokbase = (size_t)tok0;
  if (t < 32) {
    sdelta[t] = delta[tokbase + t];
    smu[t] = muv[tokbase + t];
    sirs[t] = irsv[tokbase + t];
  }
  for (int i = t; i < 32 * NX; i += 256) {
    ((float*)sB)[i] = Bm[tokbase * NX + i];
    ((float*)sC)[i] = Cm[tokbase * NX + i];
  }
  float a16[16], x16[16];
  size_t exbase = (size_t)blockIdx.x * (NX * D) + t;
  #pragma unroll
  for (int n = 0; n < 16; ++n) {
    a16[n] = At[n * D + t];
    x16[n] = EX[exbase + n * D];
  }
  float nb_d = nb[t];
  float invg = 1.0f / ng[t];
  __syncthreads();
  // scan with true entering state; hn from global, prefetched 1 iter ahead
  {
    float hv = hn[tokbase * D + t];
    for (int lo = 0; lo < CL; ++lo) {
      float hv_next = (lo + 1 < CL) ? hn[(tokbase + lo + 1) * D + t] : 0.f;
      float dlt = sdelta[lo];
      float du = dlt * hv;
      float Bv[16], Cv[16];
      *(float4*)&Bv[0]  = *(float4*)&sB[lo][0];
      *(float4*)&Bv[4]  = *(float4*)&sB[lo][4];
      *(float4*)&Bv[8]  = *(float4*)&sB[lo][8];
      *(float4*)&Bv[12] = *(float4*)&sB[lo][12];
      *(float4*)&Cv[0]  = *(float4*)&sC[lo][0];
      *(float4*)&Cv[4]  = *(float4*)&sC[lo][4];
      *(float4*)&Cv[8]  = *(float4*)&sC[lo][8];
      *(float4*)&Cv[12] = *(float4*)&sC[lo][12];
      float p = 0.f;
      #pragma unroll
      for (int n = 0; n < 16; ++n) {
        x16[n] = fmaf(exp2f(dlt * a16[n]), x16[n], du * Bv[n]);
        p = fmaf(x16[n], Cv[n], p);
      }
      float h = fmaf((hv - nb_d) * invg, sirs[lo], smu[lo]);
      s_az[lo * 260 + t] = h + p;  // final pre-LN2 value
      hv = hv_next;
    }
  }
  __syncthreads();
  // LN2 (wave w owns tokens w*8..+7) -> bf16 hi/lo A-tile, XOR-swizzled
  int dcol = t & 63, jrow = t >> 6;
  int d4 = dcol * 4, j8 = jrow * 8;
  {
    float4 g4 = ((const float4*)nfg)[dcol];
    float4 b4 = ((const float4*)nfb)[dcol];
    for (int jj = 0; jj < 8; ++jj) {
      int lo = j8 + jj;
      float4 v = *(float4*)&s_az[lo * 260 + d4];
      float s1 = v.x + v.y + v.z + v.w;
      float s2 = v.x * v.x + v.y * v.y + v.z * v.z + v.w * v.w;
      #pragma unroll
      for (int off = 1; off < 64; off <<= 1) {
        s1 += __shfl_xor(s1, off);
        s2 += __shfl_xor(s2, off);
      }
      float mu2 = s1 * (1.f / D);
      float var2 = s2 * (1.f / D) - mu2 * mu2;
      float rstd2 = rsqrtf(var2 + 1e-5f);
      float4 o;
      o.x = (v.x - mu2) * rstd2 * g4.x + b4.x;
      o.y = (v.y - mu2) * rstd2 * g4.y + b4.y;
      o.z = (v.z - mu2) * rstd2 * g4.z + b4.z;
      o.w = (v.w - mu2) * rstd2 * g4.w + b4.w;
      unsigned short h0 = f2bf(o.x), h1 = f2bf(o.y), h2 = f2bf(o.z), h3 = f2bf(o.w);
      unsigned short q0 = f2bf(o.x - bf2f(h0));
      unsigned short q1 = f2bf(o.y - bf2f(h1));
      unsigned short q2 = f2bf(o.z - bf2f(h2));
      unsigned short q3 = f2bf(o.w - bf2f(h3));
      unsigned off16 = ((unsigned)(d4 * 2)) ^ ((unsigned)(lo & 7) << 4);
      uint2 hv2, lv2;
      hv2.x = (unsigned)h0 | ((unsigned)h1 << 16);
      hv2.y = (unsigned)h2 | ((unsigned)h3 << 16);
      lv2.x = (unsigned)q0 | ((unsigned)q1 << 16);
      lv2.y = (unsigned)q2 | ((unsigned)q3 << 16);
      *(uint2*)((char*)sAh + lo * 512 + off16) = hv2;
      *(uint2*)((char*)sAl + lo * 512 + off16) = lv2;
    }
  }
  __syncthreads();
  // ---- GEMM1: (32x256) @ W1 (256x256), wave w owns cols [w*64, w*64+64) ----
  int l = t & 63, w = t >> 6;
  const bf16x8* B1h = (const bf16x8*)W1fh;
  const bf16x8* B1l = (const bf16x8*)W1fl;
  f32x4 acc[2][4];
  #pragma unroll
  for (int m = 0; m < 2; ++m)
    #pragma unroll
    for (int n = 0; n < 4; ++n) {
      f32x4 z4 = {0.f, 0.f, 0.f, 0.f};
      acc[m][n] = z4;
    }
  #pragma unroll 2
  for (int s = 0; s < 8; ++s) {
    bf16x8 ah[2], al[2];
    #pragma unroll
    for (int m = 0; m < 2; ++m) {
      int row = m * 16 + (l & 15);
      unsigned off16 = ((unsigned)(s * 64 + ((l >> 4) << 4))) ^ ((unsigned)(row & 7) << 4);
      ah[m] = *(const bf16x8*)((const char*)sAh + row * 512 + off16);
      al[m] = *(const bf16x8*)((const char*)sAl + row * 512 + off16);
    }
    #pragma unroll
    for (int n = 0; n < 4; ++n) {
      int bi = (s * 16 + w * 4 + n) * 64 + l;
      bf16x8 bh = B1h[bi];
      bf16x8 bl = B1l[bi];
      #pragma unroll
      for (int m = 0; m < 2; ++m) {
        acc[m][n] = __builtin_amdgcn_mfma_f32_16x16x32_bf16(ah[m], bh, acc[m][n], 0, 0, 0);
        acc[m][n] = __builtin_amdgcn_mfma_f32_16x16x32_bf16(al[m], bh, acc[m][n], 0, 0, 0);
        acc[m][n] = __builtin_amdgcn_mfma_f32_16x16x32_bf16(ah[m], bl, acc[m][n], 0, 0, 0);
        acc[m][n] = __builtin_amdgcn_mfma_f32_16x16x32_bf16(al[m], bl, acc[m][n], 0, 0, 0);
      }
    }
  }
  __syncthreads();  // all A-tile reads done; sAh/sAl now reused for z
  // ---- b1 + gelu + convert -> z (bf16 hi/lo) back into sAh/sAl ----
  #pragma unroll
  for (int n = 0; n < 4; ++n) {
    int colz = w * 64 + n * 16 + (l & 15);
    float b1v = b1[colz];
    #pragma unroll
    for (int m = 0; m < 2; ++m) {
      #pragma unroll
      for (int r = 0; r < 4; ++r) {
        int row = m * 16 + ((l >> 4) << 2) + r;  // C/D: row=(lane>>4)*4+reg
        float zv = gelu_exact(acc[m][n][r] + b1v);
        unsigned short zh = f2bf(zv);
        unsigned short zl = f2bf(zv - bf2f(zh));
        unsigned off16 = ((unsigned)(colz * 2)) ^ ((unsigned)(row & 7) << 4);
        *(unsigned short*)((char*)sAh + row * 512 + off16) = zh;
        *(unsigned short*)((char*)sAl + row * 512 + off16) = zl;
      }
    }
  }
  __syncthreads();
  // ---- GEMM2: z (32x256) @ W2 (256x32); wave w -> (mw=w>>1, nw=w&1) ----
  int mw = w >> 1, nw = w & 1;
  const bf16x8* B2h = (const bf16x8*)W2fh;
  const bf16x8* B2l = (const bf16x8*)W2fl;
  f32x4 acc2 = {0.f, 0.f, 0.f, 0.f};
  #pragma unroll 2
  for (int s = 0; s < 8; ++s) {
    int row = mw * 16 + (l & 15);
    unsigned off16 = ((unsigned)(s * 64 + ((l >> 4) << 4))) ^ ((unsigned)(row & 7) << 4);
    bf16x8 zh8 = *(const bf16x8*)((const char*)sAh + row * 512 + off16);
    bf16x8 zl8 = *(const bf16x8*)((const char*)sAl + row * 512 + off16);
    int bi = (s * 2 + nw) * 64 + l;
    bf16x8 bh = B2h[bi];
    bf16x8 bl = B2l[bi];
    acc2 = __builtin_amdgcn_mfma_f32_16x16x32_bf16(zh8, bh, acc2, 0, 0, 0);
    acc2 = __builtin_amdgcn_mfma_f32_16x16x32_bf16(zl8, bh, acc2, 0, 0, 0);
    acc2 = __builtin_amdgcn_mfma_f32_16x16x32_bf16(zh8, bl, acc2, 0, 0, 0);
    acc2 = __builtin_amdgcn_mfma_f32_16x16x32_bf16(zl8, bl, acc2, 0, 0, 0);
  }
  int colo = nw * 16 + (l & 15);
  float b2v = b2[colo];
  #pragma unroll
  for (int r = 0; r < 4; ++r) {
    int row = mw * 16 + ((l >> 4) << 2) + r;
    out[(size_t)(tok0 + row) * 32 + colo] = acc2[r] + b2v;
  }
}

extern "C" void kernel_launch(void* const* d_in, const int* in_sizes, int n_in,
                              void* d_out, int out_size, void* d_ws, size_t ws_size,
                              hipStream_t stream) {
  const float* y    = (const float*)d_in[0];
  const float* Win  = (const float*)d_in[1];
  const float* bin_ = (const float*)d_in[2];
  const float* ng   = (const float*)d_in[3];
  const float* nb   = (const float*)d_in[4];
  const float* A    = (const float*)d_in[5];
  const float* WB   = (const float*)d_in[6];
  const float* WC   = (const float*)d_in[7];
  const float* qd   = (const float*)d_in[8];
  const float* pd   = (const float*)d_in[9];
  const float* nfg  = (const float*)d_in[10];
  const float* nfb  = (const float*)d_in[11];
  const float* W1   = (const float*)d_in[12];
  const float* b1   = (const float*)d_in[13];
  const float* W2   = (const float*)d_in[14];
  const float* b2   = (const float*)d_in[15];

  float* ws = (float*)d_ws;
  float* hnbuf = ws;                          // NTOK*D
  float* delta = ws + 4194304;                // NTOK
  float* Bm    = delta + NTOK;                // NTOK*NX
  float* Cm    = Bm + NTOK * NX;              // NTOK*NX
  float* muv   = Cm + NTOK * NX;              // NTOK
  float* irsv  = muv + NTOK;                  // NTOK
  float* Tbuf  = irsv + NTOK;                 // 512
  float* At    = Tbuf + NBATCH * NCH;         // 4096
  float* EX    = At + D * NX;                 // 512*4096 = 2M floats
  // bf16 fragment-packed weights (hi/lo)
  unsigned short* W1fh  = (unsigned short*)(EX + 2097152);  // 65536
  unsigned short* W1fl  = W1fh + 65536;                     // 65536
  unsigned short* W2fh  = W1fl + 65536;                     // 8192
  unsigned short* W2fl  = W2fh + 8192;                      // 8192
  unsigned short* Winfh = W2fl + 8192;                      // 8192
  unsigned short* Winfl = Winfh + 8192;                     // 8192
  unsigned short* Wbcfh = Winfl + 8192;                     // 8192
  unsigned short* Wbcfl = Wbcfh + 8192;                     // 8192

  k0_prep<<<368, 256, 0, stream>>>(A, WB, WC, Win, W1, W2, At,
                                   W1fh, W1fl, W2fh, W2fl,
                                   Winfh, Winfl, Wbcfh, Wbcfl);
  k1a_front_scan<<<NTOK / 32, 512, 0, stream>>>(y, bin_, ng, nb, qd, pd, At,
                                                Winfh, Winfl, Wbcfh, Wbcfl,
                                                hnbuf, delta, Bm, Cm,
                                                muv, irsv, EX, Tbuf);
  k2b_chunkscan<<<NBATCH * 64, 64, 0, stream>>>(At, Tbuf, EX);
  k2cd_scan_mlp<<<NTOK / 32, 256, 0, stream>>>(hnbuf, delta, Bm, Cm, At, EX,
                                               muv, irsv, ng, nb, nfg, nfb,
                                               W1fh, W1fl, W2fh, W2fl,
                                               b1, b2, (float*)d_out);
}

// Round 13
// 180.295 us; speedup vs baseline: 1.0789x; 1.0277x over previous
//
#include <hip/hip_runtime.h>
#include <math.h>

#define D 256
#define NX 16
#define L 2048
#define NBATCH 8
#define NTOK (NBATCH * L)
#define CL 32
#define NCH (L / CL)  // 64
#define LOG2E 1.44269504088896340736f

typedef float f32x4 __attribute__((ext_vector_type(4)));
// Fragment type for mfma_f32_16x16x32_bf16 on gfx950: 8 bf16 as 8 shorts.
typedef short bf16x8 __attribute__((ext_vector_type(8)));

// round-to-nearest-even f32 -> bf16 (as ushort bits)
__device__ __forceinline__ unsigned short f2bf(float x) {
  unsigned u = __float_as_uint(x);
  u = u + 0x7fffu + ((u >> 16) & 1u);
  return (unsigned short)(u >> 16);
}
__device__ __forceinline__ float bf2f(unsigned short h) {
  return __uint_as_float(((unsigned)h) << 16);
}

// ---------------- K0: At prep + ALL weight fragment packing (hi/lo bf16) ----
__global__ __launch_bounds__(256) void k0_prep(const float* __restrict__ A,
                                               const float* __restrict__ WB,
                                               const float* __restrict__ WC,
                                               const float* __restrict__ Win,
                                               const float* __restrict__ W1,
                                               const float* __restrict__ W2,
                                               float* __restrict__ At,
                                               unsigned short* __restrict__ W1fh,
                                               unsigned short* __restrict__ W1fl,
                                               unsigned short* __restrict__ W2fh,
                                               unsigned short* __restrict__ W2fl,
                                               unsigned short* __restrict__ Winfh,
                                               unsigned short* __restrict__ Winfl,
                                               unsigned short* __restrict__ Wbcfh,
                                               unsigned short* __restrict__ Wbcfl) {
  int i = blockIdx.x * 256 + threadIdx.x;  // 94208 total
  if (i < 4096) {
    int d = i >> 4, n = i & 15;
    At[n * D + d] = A[i] * LOG2E;
  } else if (i < 12288) {
    // Win frags (B of phase A, K=32): e = (tt*64 + l)*8 + j, tt=0..15
    int e = i - 4096;
    int j = e & 7, l = (e >> 3) & 63, tt = e >> 9;
    int k = ((l >> 4) << 3) + j;        // K=32, single K-step
    int n = tt * 16 + (l & 15);
    float x = Win[k * 256 + n];
    unsigned short h = f2bf(x);
    Winfh[e] = h;
    Winfl[e] = f2bf(x - bf2f(h));
  } else if (i < 20480) {
    // Wbct frags (B of phase C): e = ((s*2+tt)*64 + l)*8 + j
    int e = i - 12288;
    int j = e & 7, l = (e >> 3) & 63, q = e >> 9;  // q = s*2+tt
    int s = q >> 1, tt = q & 1;
    int k = s * 32 + ((l >> 4) << 3) + j;
    int n = tt * 16 + (l & 15);
    float x = (n < 16) ? WB[n * 256 + k] : WC[(n - 16) * 256 + k];
    unsigned short h = f2bf(x);
    Wbcfh[e] = h;
    Wbcfl[e] = f2bf(x - bf2f(h));
  } else if (i < 86016) {
    // W1 frags: e = ((s*16 + t)*64 + l)*8 + j ; 65536 elems
    int e = i - 20480;
    int j = e & 7, l = (e >> 3) & 63, tt = (e >> 9) & 15, s = e >> 13;
    int k = s * 32 + ((l >> 4) << 3) + j;
    int n = tt * 16 + (l & 15);
    float x = W1[k * 256 + n];
    unsigned short h = f2bf(x);
    W1fh[e] = h;
    W1fl[e] = f2bf(x - bf2f(h));
  } else {
    // W2 frags: e = ((s*2 + t)*64 + l)*8 + j ; 8192 elems
    int e = i - 86016;
    int j = e & 7, l = (e >> 3) & 63, tt = (e >> 9) & 1, s = e >> 10;
    int k = s * 32 + ((l >> 4) << 3) + j;
    int n = tt * 16 + (l & 15);
    float x = W2[k * 32 + n];
    unsigned short h = f2bf(x);
    W2fh[e] = h;
    W2fl[e] = f2bf(x - bf2f(h));
  }
}

// ---------------- K1A: MFMA front end + LOCAL CHUNK SCAN, 512 thr ----------
// r12 + (a) step 6 computes inclusive delta prefix (cds15 at tok 15, T at 31);
// (b) step-8 scan split in halves, emitting EXmid (local state after 16 steps)
// so k2cd can run 16-token tiles.
__global__ __launch_bounds__(512, 4) void k1a_front_scan(
    const float* __restrict__ y, const float* __restrict__ bin_,
    const float* __restrict__ ng, const float* __restrict__ nb,
    const float* __restrict__ qd, const float* __restrict__ pd,
    const float* __restrict__ At,
    const unsigned short* __restrict__ Winfh,
    const unsigned short* __restrict__ Winfl,
    const unsigned short* __restrict__ Wbcfh,
    const unsigned short* __restrict__ Wbcfl,
    float* __restrict__ hn, float* __restrict__ delta,
    float* __restrict__ Bm, float* __restrict__ Cm,
    float* __restrict__ muv, float* __restrict__ irsv,
    float* __restrict__ EX, float* __restrict__ EXmid,
    float* __restrict__ cds15g, float* __restrict__ T) {
  __shared__ float sy[32][36];       // y tile, padded pitch (bank spread)
  __shared__ float sh[32][260];      // hn tile f32, pitch 260
  __shared__ float sB[32][NX];
  __shared__ float sred[32][16];     // per-wave LN/delta partials
  __shared__ float sdelta[32];
  __shared__ float smu[32];
  __shared__ float srstd[32];
  __shared__ __align__(16) unsigned short sChA_h[32 * 256];  // hn bf16 hi (swz)
  __shared__ __align__(16) unsigned short sChA_l[32 * 256];  // hn bf16 lo (swz)
  int t = threadIdx.x;
  int l = t & 63;
  int w = t >> 6;
  int tok0 = blockIdx.x * 32;
  // 1. stage y (32x32 f32)
  if (t < 256) {
    int row = t >> 3, c4 = t & 7;
    *(float4*)&sy[row][c4 * 4] = ((const float4*)(y + (size_t)tok0 * 32))[t];
  }
  __syncthreads();
  // 2. phase A MFMA: build y A-frags (hi/lo), Win B-frags from global
  f32x4 acc[2][2];
  {
    bf16x8 yah[2], yal[2];
    int k0 = (l >> 4) << 3;
    #pragma unroll
    for (int m = 0; m < 2; ++m) {
      int row = m * 16 + (l & 15);
      float4 f0 = *(float4*)&sy[row][k0];
      float4 f1 = *(float4*)&sy[row][k0 + 4];
      float v0 = f0.x, v1_ = f0.y, v2 = f0.z, v3 = f0.w;
      float v4 = f1.x, v5 = f1.y, v6 = f1.z, v7 = f1.w;
      unsigned short h0 = f2bf(v0), h1 = f2bf(v1_), h2 = f2bf(v2), h3 = f2bf(v3);
      unsigned short h4 = f2bf(v4), h5 = f2bf(v5), h6 = f2bf(v6), h7 = f2bf(v7);
      yah[m][0] = (short)h0; yah[m][1] = (short)h1; yah[m][2] = (short)h2; yah[m][3] = (short)h3;
      yah[m][4] = (short)h4; yah[m][5] = (short)h5; yah[m][6] = (short)h6; yah[m][7] = (short)h7;
      yal[m][0] = (short)f2bf(v0 - bf2f(h0)); yal[m][1] = (short)f2bf(v1_ - bf2f(h1));
      yal[m][2] = (short)f2bf(v2 - bf2f(h2)); yal[m][3] = (short)f2bf(v3 - bf2f(h3));
      yal[m][4] = (short)f2bf(v4 - bf2f(h4)); yal[m][5] = (short)f2bf(v5 - bf2f(h5));
      yal[m][6] = (short)f2bf(v6 - bf2f(h6)); yal[m][7] = (short)f2bf(v7 - bf2f(h7));
    }
    const bf16x8* Bh = (const bf16x8*)Winfh;
    const bf16x8* Bl = (const bf16x8*)Winfl;
    #pragma unroll
    for (int n = 0; n < 2; ++n) {
      int tt = w * 2 + n;
      bf16x8 bh = Bh[tt * 64 + l];
      bf16x8 bl = Bl[tt * 64 + l];
      #pragma unroll
      for (int m = 0; m < 2; ++m) {
        f32x4 a = {0.f, 0.f, 0.f, 0.f};
        a = __builtin_amdgcn_mfma_f32_16x16x32_bf16(yah[m], bh, a, 0, 0, 0);
        a = __builtin_amdgcn_mfma_f32_16x16x32_bf16(yal[m], bh, a, 0, 0, 0);
        a = __builtin_amdgcn_mfma_f32_16x16x32_bf16(yah[m], bl, a, 0, 0, 0);
        a = __builtin_amdgcn_mfma_f32_16x16x32_bf16(yal[m], bl, a, 0, 0, 0);
        acc[m][n] = a;
      }
    }
  }
  // bias add: lane's two cols
  int c0 = w * 32 + (l & 15), c1 = c0 + 16;
  {
    float b0 = bin_[c0], b1v = bin_[c1];
    #pragma unroll
    for (int m = 0; m < 2; ++m)
      #pragma unroll
      for (int r = 0; r < 4; ++r) { acc[m][0][r] += b0; acc[m][1][r] += b1v; }
  }
  // 3. LN partial reduce over this wave's 32 cols (16-lane groups)
  {
    #pragma unroll
    for (int m = 0; m < 2; ++m)
      #pragma unroll
      for (int r = 0; r < 4; ++r) {
        float a0 = acc[m][0][r], a1 = acc[m][1][r];
        float s1 = a0 + a1;
        float s2 = a0 * a0 + a1 * a1;
        #pragma unroll
        for (int off = 1; off < 16; off <<= 1) {
          s1 += __shfl_xor(s1, off);
          s2 += __shfl_xor(s2, off);
        }
        if ((l & 15) == 0) {
          int tok = m * 16 + ((l >> 4) << 2) + r;
          sred[tok][w * 2] = s1;
          sred[tok][w * 2 + 1] = s2;
        }
      }
  }
  __syncthreads();
  // 4. combine partials -> mu, rstd (threads 0..31)
  if (t < 32) {
    float s1 = 0.f, s2 = 0.f;
    #pragma unroll
    for (int q = 0; q < 8; ++q) { s1 += sred[t][q * 2]; s2 += sred[t][q * 2 + 1]; }
    float mu = s1 * (1.f / D);
    float var = s2 * (1.f / D) - mu * mu;
    float rstd = rsqrtf(var + 1e-5f);
    smu[t] = mu;
    srstd[t] = rstd;
    muv[tok0 + t] = mu;
    irsv[tok0 + t] = sqrtf(var + 1e-5f);
  }
  __syncthreads();
  // 5. hn = LN(h); write sh f32; delta partial reduce
  {
    float g0 = ng[c0], g1 = ng[c1];
    float nb0 = nb[c0], nb1 = nb[c1];
    float q0 = qd[c0], q1 = qd[c1];
    float ddv[2][4];
    #pragma unroll
    for (int m = 0; m < 2; ++m)
      #pragma unroll
      for (int r = 0; r < 4; ++r) {
        int tok = m * 16 + ((l >> 4) << 2) + r;
        float mu = smu[tok], rstd = srstd[tok];
        float h0 = (acc[m][0][r] - mu) * rstd * g0 + nb0;
        float h1 = (acc[m][1][r] - mu) * rstd * g1 + nb1;
        sh[tok][c0] = h0;
        sh[tok][c1] = h1;
        float dx = h0 * q0 + h1 * q1;
        #pragma unroll
        for (int off = 1; off < 16; off <<= 1) dx += __shfl_xor(dx, off);
        ddv[m][r] = dx;
      }
    if ((l & 15) == 0) {
      #pragma unroll
      for (int m = 0; m < 2; ++m)
        #pragma unroll
        for (int r = 0; r < 4; ++r)
          sred[m * 16 + ((l >> 4) << 2) + r][w] = ddv[m][r];
    }
  }
  __syncthreads();
  // 6. delta combine + inclusive prefix (cds15, T) ; sh -> bf16 hi/lo swizzled
  if (t < 32) {
    float dsum = 0.f;
    #pragma unroll
    for (int q = 0; q < 8; ++q) dsum += sred[t][q];
    float xx = pd[0] + dsum;
    float dv = (xx > 20.f) ? xx : log1pf(expf(xx));
    delta[tok0 + t] = dv;
    sdelta[t] = dv;
    float c = dv;
    #pragma unroll
    for (int off = 1; off < 32; off <<= 1) {
      float o = __shfl_up(c, off);
      if (t >= off) c += o;
    }
    if (t == 15) cds15g[blockIdx.x] = c;
    if (t == 31) T[blockIdx.x] = c;
  }
  {
    int row = t & 31;
    int cq = (t >> 5) * 16;   // 16 cols per thread
    float4 f0 = *(float4*)&sh[row][cq];
    float4 f1 = *(float4*)&sh[row][cq + 4];
    float4 f2 = *(float4*)&sh[row][cq + 8];
    float4 f3 = *(float4*)&sh[row][cq + 12];
    float vv[16] = {f0.x, f0.y, f0.z, f0.w, f1.x, f1.y, f1.z, f1.w,
                    f2.x, f2.y, f2.z, f2.w, f3.x, f3.y, f3.z, f3.w};
    unsigned hw[8], lw[8];
    #pragma unroll
    for (int p = 0; p < 8; ++p) {
      unsigned short ha = f2bf(vv[2 * p]), hb = f2bf(vv[2 * p + 1]);
      unsigned short la = f2bf(vv[2 * p] - bf2f(ha));
      unsigned short lb = f2bf(vv[2 * p + 1] - bf2f(hb));
      hw[p] = (unsigned)ha | ((unsigned)hb << 16);
      lw[p] = (unsigned)la | ((unsigned)lb << 16);
    }
    unsigned base = (unsigned)row * 512;
    #pragma unroll
    for (int g = 0; g < 2; ++g) {
      unsigned off = ((unsigned)(cq * 2 + g * 16)) ^ ((unsigned)(row & 7) << 4);
      uint4 hv4 = {hw[g * 4], hw[g * 4 + 1], hw[g * 4 + 2], hw[g * 4 + 3]};
      uint4 lv4 = {lw[g * 4], lw[g * 4 + 1], lw[g * 4 + 2], lw[g * 4 + 3]};
      *(uint4*)((char*)sChA_h + base + off) = hv4;
      *(uint4*)((char*)sChA_l + base + off) = lv4;
    }
  }
  __syncthreads();
  // 7. phase C MFMA (waves 0-3); waves 4-7: hn -> global copy (coalesced)
  if (w < 4) {
    int mw = w & 1, nw = w >> 1;
    int row = mw * 16 + (l & 15);
    unsigned abase = (unsigned)row * 512;
    const bf16x8* B2h = (const bf16x8*)Wbcfh;
    const bf16x8* B2l = (const bf16x8*)Wbcfl;
    f32x4 acc2 = {0.f, 0.f, 0.f, 0.f};
    #pragma unroll
    for (int s = 0; s < 8; ++s) {
      unsigned off = ((unsigned)(s * 64 + ((l >> 4) << 4))) ^ ((unsigned)(row & 7) << 4);
      bf16x8 ah = *(const bf16x8*)((const char*)sChA_h + abase + off);
      bf16x8 al = *(const bf16x8*)((const char*)sChA_l + abase + off);
      int bi = (s * 2 + nw) * 64 + l;
      bf16x8 bh = B2h[bi];
      bf16x8 bl = B2l[bi];
      acc2 = __builtin_amdgcn_mfma_f32_16x16x32_bf16(ah, bh, acc2, 0, 0, 0);
      acc2 = __builtin_amdgcn_mfma_f32_16x16x32_bf16(al, bh, acc2, 0, 0, 0);
      acc2 = __builtin_amdgcn_mfma_f32_16x16x32_bf16(ah, bl, acc2, 0, 0, 0);
      acc2 = __builtin_amdgcn_mfma_f32_16x16x32_bf16(al, bl, acc2, 0, 0, 0);
    }
    int tokr = mw * 16 + ((l >> 4) << 2);
    int colc = l & 15;
    if (nw == 0) {
      #pragma unroll
      for (int r = 0; r < 4; ++r) {
        Bm[(size_t)(tok0 + tokr + r) * NX + colc] = acc2[r];
        sB[tokr + r][colc] = acc2[r];
      }
    } else {
      #pragma unroll
      for (int r = 0; r < 4; ++r)
        Cm[(size_t)(tok0 + tokr + r) * NX + colc] = acc2[r];
    }
  } else {
    float4* dst = (float4*)(hn + (size_t)tok0 * D);
    for (int i = t - 256; i < 2048; i += 256) {
      int row = i >> 6, c4 = i & 63;
      dst[i] = *(float4*)&sh[row][c4 * 4];
    }
  }
  __syncthreads();
  // 8. scan: n-split halves; split loop to emit EXmid (local mid state).
  {
    int half = t >> 8;          // 0: n=0..7, 1: n=8..15
    int d = t & 255;
    float a8[8], x8[8];
    #pragma unroll
    for (int n = 0; n < 8; ++n) {
      a8[n] = At[(half * 8 + n) * D + d];
      x8[n] = 0.f;
    }
    size_t exbase = (size_t)blockIdx.x * (NX * D) + d;
    for (int lo = 0; lo < 16; ++lo) {
      float dlt = sdelta[lo];
      float du = dlt * sh[lo][d];
      float Bv[8];
      *(float4*)&Bv[0] = *(float4*)&sB[lo][half * 8];
      *(float4*)&Bv[4] = *(float4*)&sB[lo][half * 8 + 4];
      #pragma unroll
      for (int n = 0; n < 8; ++n)
        x8[n] = fmaf(exp2f(dlt * a8[n]), x8[n], du * Bv[n]);
    }
    #pragma unroll
    for (int n = 0; n < 8; ++n) EXmid[exbase + (half * 8 + n) * D] = x8[n];
    for (int lo = 16; lo < 32; ++lo) {
      float dlt = sdelta[lo];
      float du = dlt * sh[lo][d];
      float Bv[8];
      *(float4*)&Bv[0] = *(float4*)&sB[lo][half * 8];
      *(float4*)&Bv[4] = *(float4*)&sB[lo][half * 8 + 4];
      #pragma unroll
      for (int n = 0; n < 8; ++n)
        x8[n] = fmaf(exp2f(dlt * a8[n]), x8[n], du * Bv[n]);
    }
    #pragma unroll
    for (int n = 0; n < 8; ++n) EX[exbase + (half * 8 + n) * D] = x8[n];
  }
}

// ---------------- K2b: chunk-level scan, 8-deep prefetch ring --------------
__global__ __launch_bounds__(64) void k2b_chunkscan(
    const float* __restrict__ At, const float* __restrict__ T,
    float* __restrict__ EX) {
  __shared__ float sT[NCH];
  int b = blockIdx.x >> 6;
  int rem = ((blockIdx.x & 63) << 6) | threadIdx.x;  // n*D + d
  sT[threadIdx.x] = T[b * NCH + threadIdx.x];
  __syncthreads();
  float A2 = At[rem];  // already *LOG2E
  size_t base = ((size_t)b << 18) + rem;
  float eq[8];
  #pragma unroll
  for (int j = 0; j < 8; ++j) eq[j] = EX[base + ((size_t)j << 12)];
  float x = 0.f;
  #pragma unroll 8
  for (int c = 0; c < NCH; ++c) {
    float e = eq[c & 7];
    if (c + 8 < NCH) eq[c & 7] = EX[base + ((size_t)(c + 8) << 12)];
    EX[base + ((size_t)c << 12)] = x;
    x = fmaf(exp2f(sT[c] * A2), x, e);
  }
}

__device__ __forceinline__ float gelu_exact(float x) {
  return 0.5f * x * (1.f + erff(x * 0.70710678118654752440f));
}

// ---------------- K2cd: 16-TOKEN TILES: scan + LN2 + MFMA MLP ---------------
// Grid 1024 (2 tiles per 32-chunk) -> 4 independent blocks/CU. Tile half=1
// reconstructs entering state = exp2(cds15*At)*EX + EXmid. Phases identical
// to r6 structure, halved rows. LDS ~38 KB.
__global__ __launch_bounds__(256, 4) void k2cd_scan_mlp(
    const float* __restrict__ hn, const float* __restrict__ delta,
    const float* __restrict__ Bm, const float* __restrict__ Cm,
    const float* __restrict__ At, const float* __restrict__ EX,
    const float* __restrict__ EXmid, const float* __restrict__ cds15g,
    const float* __restrict__ muv, const float* __restrict__ irsv,
    const float* __restrict__ ng, const float* __restrict__ nb,
    const float* __restrict__ nfg, const float* __restrict__ nfb,
    const unsigned short* __restrict__ W1fh, const unsigned short* __restrict__ W1fl,
    const unsigned short* __restrict__ W2fh, const unsigned short* __restrict__ W2fl,
    const float* __restrict__ b1, const float* __restrict__ b2,
    float* __restrict__ out) {
  __shared__ float s_az[16 * 260];                       // scan output (pre-LN2)
  __shared__ __align__(16) unsigned short sAh[16 * 256]; // bf16 hi (a-tile, then z)
  __shared__ __align__(16) unsigned short sAl[16 * 256]; // bf16 lo
  __shared__ float sB[16][NX];
  __shared__ float sC[16][NX];
  __shared__ float sdelta[16];
  __shared__ float smu[16];
  __shared__ float sirs[16];
  int t = threadIdx.x;
  int chunk = blockIdx.x >> 1;
  int half = blockIdx.x & 1;
  int tok0 = blockIdx.x * 16;
  size_t tokbase = (size_t)tok0;
  if (t < 16) {
    sdelta[t] = delta[tokbase + t];
    smu[t] = muv[tokbase + t];
    sirs[t] = irsv[tokbase + t];
  }
  // sB/sC: 256 floats each; one element per thread
  ((float*)sB)[t] = Bm[tokbase * NX + t];
  ((float*)sC)[t] = Cm[tokbase * NX + t];
  float a16[16], x16[16];
  size_t exbase = (size_t)chunk * (NX * D) + t;
  #pragma unroll
  for (int n = 0; n < 16; ++n) {
    a16[n] = At[n * D + t];
    x16[n] = EX[exbase + n * D];
  }
  if (half) {
    float c15 = cds15g[chunk];   // uniform scalar
    #pragma unroll
    for (int n = 0; n < 16; ++n)
      x16[n] = fmaf(exp2f(c15 * a16[n]), x16[n], EXmid[exbase + n * D]);
  }
  float nb_d = nb[t];
  float invg = 1.0f / ng[t];
  __syncthreads();
  // scan (16 iters) with true entering state; hn prefetched 1 ahead
  {
    float hv = hn[tokbase * D + t];
    for (int lo = 0; lo < 16; ++lo) {
      float hv_next = (lo + 1 < 16) ? hn[(tokbase + lo + 1) * D + t] : 0.f;
      float dlt = sdelta[lo];
      float du = dlt * hv;
      float Bv[16], Cv[16];
      *(float4*)&Bv[0]  = *(float4*)&sB[lo][0];
      *(float4*)&Bv[4]  = *(float4*)&sB[lo][4];
      *(float4*)&Bv[8]  = *(float4*)&sB[lo][8];
      *(float4*)&Bv[12] = *(float4*)&sB[lo][12];
      *(float4*)&Cv[0]  = *(float4*)&sC[lo][0];
      *(float4*)&Cv[4]  = *(float4*)&sC[lo][4];
      *(float4*)&Cv[8]  = *(float4*)&sC[lo][8];
      *(float4*)&Cv[12] = *(float4*)&sC[lo][12];
      float p = 0.f;
      #pragma unroll
      for (int n = 0; n < 16; ++n) {
        x16[n] = fmaf(exp2f(dlt * a16[n]), x16[n], du * Bv[n]);
        p = fmaf(x16[n], Cv[n], p);
      }
      float h = fmaf((hv - nb_d) * invg, sirs[lo], smu[lo]);
      s_az[lo * 260 + t] = h + p;  // final pre-LN2 value
      hv = hv_next;
    }
  }
  __syncthreads();
  // LN2 (wave w owns tokens w*4..+3) -> bf16 hi/lo A-tile, XOR-swizzled
  int dcol = t & 63, jrow = t >> 6;
  int d4 = dcol * 4, j4 = jrow * 4;
  {
    float4 g4 = ((const float4*)nfg)[dcol];
    float4 b4 = ((const float4*)nfb)[dcol];
    for (int jj = 0; jj < 4; ++jj) {
      int lo = j4 + jj;
      float4 v = *(float4*)&s_az[lo * 260 + d4];
      float s1 = v.x + v.y + v.z + v.w;
      float s2 = v.x * v.x + v.y * v.y + v.z * v.z + v.w * v.w;
      #pragma unroll
      for (int off = 1; off < 64; off <<= 1) {
        s1 += __shfl_xor(s1, off);
        s2 += __shfl_xor(s2, off);
      }
      float mu2 = s1 * (1.f / D);
      float var2 = s2 * (1.f / D) - mu2 * mu2;
      float rstd2 = rsqrtf(var2 + 1e-5f);
      float4 o;
      o.x = (v.x - mu2) * rstd2 * g4.x + b4.x;
      o.y = (v.y - mu2) * rstd2 * g4.y + b4.y;
      o.z = (v.z - mu2) * rstd2 * g4.z + b4.z;
      o.w = (v.w - mu2) * rstd2 * g4.w + b4.w;
      unsigned short h0 = f2bf(o.x), h1 = f2bf(o.y), h2 = f2bf(o.z), h3 = f2bf(o.w);
      unsigned short q0 = f2bf(o.x - bf2f(h0));
      unsigned short q1 = f2bf(o.y - bf2f(h1));
      unsigned short q2 = f2bf(o.z - bf2f(h2));
      unsigned short q3 = f2bf(o.w - bf2f(h3));
      unsigned off16 = ((unsigned)(d4 * 2)) ^ ((unsigned)(lo & 7) << 4);
      uint2 hv2, lv2;
      hv2.x = (unsigned)h0 | ((unsigned)h1 << 16);
      hv2.y = (unsigned)h2 | ((unsigned)h3 << 16);
      lv2.x = (unsigned)q0 | ((unsigned)q1 << 16);
      lv2.y = (unsigned)q2 | ((unsigned)q3 << 16);
      *(uint2*)((char*)sAh + lo * 512 + off16) = hv2;
      *(uint2*)((char*)sAl + lo * 512 + off16) = lv2;
    }
  }
  __syncthreads();
  // ---- GEMM1: (16x256) @ W1 (256x256), wave w owns cols [w*64, w*64+64) ----
  int l = t & 63, w = t >> 6;
  const bf16x8* B1h = (const bf16x8*)W1fh;
  const bf16x8* B1l = (const bf16x8*)W1fl;
  f32x4 acc[4];
  #pragma unroll
  for (int n = 0; n < 4; ++n) {
    f32x4 z4 = {0.f, 0.f, 0.f, 0.f};
    acc[n] = z4;
  }
  #pragma unroll 2
  for (int s = 0; s < 8; ++s) {
    int row = l & 15;
    unsigned off16 = ((unsigned)(s * 64 + ((l >> 4) << 4))) ^ ((unsigned)(row & 7) << 4);
    bf16x8 ah = *(const bf16x8*)((const char*)sAh + row * 512 + off16);
    bf16x8 al = *(const bf16x8*)((const char*)sAl + row * 512 + off16);
    #pragma unroll
    for (int n = 0; n < 4; ++n) {
      int bi = (s * 16 + w * 4 + n) * 64 + l;
      bf16x8 bh = B1h[bi];
      bf16x8 bl = B1l[bi];
      acc[n] = __builtin_amdgcn_mfma_f32_16x16x32_bf16(ah, bh, acc[n], 0, 0, 0);
      acc[n] = __builtin_amdgcn_mfma_f32_16x16x32_bf16(al, bh, acc[n], 0, 0, 0);
      acc[n] = __builtin_amdgcn_mfma_f32_16x16x32_bf16(ah, bl, acc[n], 0, 0, 0);
      acc[n] = __builtin_amdgcn_mfma_f32_16x16x32_bf16(al, bl, acc[n], 0, 0, 0);
    }
  }
  __syncthreads();  // all A-tile reads done; sAh/sAl now reused for z
  // ---- b1 + gelu + convert -> z (bf16 hi/lo) back into sAh/sAl ----
  #pragma unroll
  for (int n = 0; n < 4; ++n) {
    int colz = w * 64 + n * 16 + (l & 15);
    float b1v = b1[colz];
    #pragma unroll
    for (int r = 0; r < 4; ++r) {
      int row = ((l >> 4) << 2) + r;  // C/D: row=(lane>>4)*4+reg (0..15)
      float zv = gelu_exact(acc[n][r] + b1v);
      unsigned short zh = f2bf(zv);
      unsigned short zl = f2bf(zv - bf2f(zh));
      unsigned off16 = ((unsigned)(colz * 2)) ^ ((unsigned)(row & 7) << 4);
      *(unsigned short*)((char*)sAh + row * 512 + off16) = zh;
      *(unsigned short*)((char*)sAl + row * 512 + off16) = zl;
    }
  }
  __syncthreads();
  // ---- GEMM2: z (16x256) @ W2 (256x32); waves 0-1 (nw = w) ----
  if (w < 2) {
    int nw = w;
    const bf16x8* B2h = (const bf16x8*)W2fh;
    const bf16x8* B2l = (const bf16x8*)W2fl;
    f32x4 acc2 = {0.f, 0.f, 0.f, 0.f};
    #pragma unroll 2
    for (int s = 0; s < 8; ++s) {
      int row = l & 15;
      unsigned off16 = ((unsigned)(s * 64 + ((l >> 4) << 4))) ^ ((unsigned)(row & 7) << 4);
      bf16x8 zh8 = *(const bf16x8*)((const char*)sAh + row * 512 + off16);
      bf16x8 zl8 = *(const bf16x8*)((const char*)sAl + row * 512 + off16);
      int bi = (s * 2 + nw) * 64 + l;
      bf16x8 bh = B2h[bi];
      bf16x8 bl = B2l[bi];
      acc2 = __builtin_amdgcn_mfma_f32_16x16x32_bf16(zh8, bh, acc2, 0, 0, 0);
      acc2 = __builtin_amdgcn_mfma_f32_16x16x32_bf16(zl8, bh, acc2, 0, 0, 0);
      acc2 = __builtin_amdgcn_mfma_f32_16x16x32_bf16(zh8, bl, acc2, 0, 0, 0);
      acc2 = __builtin_amdgcn_mfma_f32_16x16x32_bf16(zl8, bl, acc2, 0, 0, 0);
    }
    int colo = nw * 16 + (l & 15);
    float b2v = b2[colo];
    #pragma unroll
    for (int r = 0; r < 4; ++r) {
      int row = ((l >> 4) << 2) + r;
      out[(size_t)(tok0 + row) * 32 + colo] = acc2[r] + b2v;
    }
  }
}

extern "C" void kernel_launch(void* const* d_in, const int* in_sizes, int n_in,
                              void* d_out, int out_size, void* d_ws, size_t ws_size,
                              hipStream_t stream) {
  const float* y    = (const float*)d_in[0];
  const float* Win  = (const float*)d_in[1];
  const float* bin_ = (const float*)d_in[2];
  const float* ng   = (const float*)d_in[3];
  const float* nb   = (const float*)d_in[4];
  const float* A    = (const float*)d_in[5];
  const float* WB   = (const float*)d_in[6];
  const float* WC   = (const float*)d_in[7];
  const float* qd   = (const float*)d_in[8];
  const float* pd   = (const float*)d_in[9];
  const float* nfg  = (const float*)d_in[10];
  const float* nfb  = (const float*)d_in[11];
  const float* W1   = (const float*)d_in[12];
  const float* b1   = (const float*)d_in[13];
  const float* W2   = (const float*)d_in[14];
  const float* b2   = (const float*)d_in[15];

  float* ws = (float*)d_ws;
  float* hnbuf = ws;                          // NTOK*D
  float* delta = ws + 4194304;                // NTOK
  float* Bm    = delta + NTOK;                // NTOK*NX
  float* Cm    = Bm + NTOK * NX;              // NTOK*NX
  float* muv   = Cm + NTOK * NX;              // NTOK
  float* irsv  = muv + NTOK;                  // NTOK
  float* Tbuf  = irsv + NTOK;                 // 512
  float* cds15 = Tbuf + NBATCH * NCH;         // 512
  float* At    = cds15 + NBATCH * NCH;        // 4096
  float* EX    = At + D * NX;                 // 512*4096 = 2M floats
  float* EXmid = EX + 2097152;                // 2M floats
  // bf16 fragment-packed weights (hi/lo)
  unsigned short* W1fh  = (unsigned short*)(EXmid + 2097152); // 65536
  unsigned short* W1fl  = W1fh + 65536;                     // 65536
  unsigned short* W2fh  = W1fl + 65536;                     // 8192
  unsigned short* W2fl  = W2fh + 8192;                      // 8192
  unsigned short* Winfh = W2fl + 8192;                      // 8192
  unsigned short* Winfl = Winfh + 8192;                     // 8192
  unsigned short* Wbcfh = Winfl + 8192;                     // 8192
  unsigned short* Wbcfl = Wbcfh + 8192;                     // 8192

  k0_prep<<<368, 256, 0, stream>>>(A, WB, WC, Win, W1, W2, At,
                                   W1fh, W1fl, W2fh, W2fl,
                                   Winfh, Winfl, Wbcfh, Wbcfl);
  k1a_front_scan<<<NTOK / 32, 512, 0, stream>>>(y, bin_, ng, nb, qd, pd, At,
                                                Winfh, Winfl, Wbcfh, Wbcfl,
                                                hnbuf, delta, Bm, Cm,
                                                muv, irsv, EX, EXmid,
                                                cds15, Tbuf);
  k2b_chunkscan<<<NBATCH * 64, 64, 0, stream>>>(At, Tbuf, EX);
  k2cd_scan_mlp<<<NTOK / 16, 256, 0, stream>>>(hnbuf, delta, Bm, Cm, At, EX,
                                               EXmid, cds15,
                                               muv, irsv, ng, nb, nfg, nfb,
                                               W1fh, W1fl, W2fh, W2fl,
                                               b1, b2, (float*)d_out);
}